// Round 1
// baseline (461.850 us; speedup 1.0000x reference)
//
#include <hip/hip_runtime.h>
#include <hip/hip_bf16.h>
#include <cstdint>
#include <cstddef>

// ---------------------------------------------------------------------------
// 3-layer GCN: h1 = relu(A @ (x@W1) + b1); h2 = relu(A @ (h1@W2) + b2);
// out = log_softmax(A @ (h2@Wf) + bf)
// A = D^-1/2 (Adj + I) D^-1/2  (symmetric GCN norm with self-loops)
//
// Strategy: build CSR-by-dst once per call (count + scan + scatter), then
// per-layer: dense fp32 GEMM (LDS-tiled, vector ALU — no fp32 MFMA on CDNA4)
// followed by a wave-per-node gather-aggregate (no atomics in the hot path).
// ---------------------------------------------------------------------------

#define WAVE 64

__global__ void k_count(const int* __restrict__ dst, int E, int* __restrict__ cnt, int N) {
    int e = blockIdx.x * blockDim.x + threadIdx.x;
    if (e >= E) return;
    int d = dst[e];
    if (d >= 0 && d < N) atomicAdd(&cnt[d], 1);
}

__global__ void k_dinv(const int* __restrict__ cnt, float* __restrict__ dinv, int N) {
    int i = blockIdx.x * blockDim.x + threadIdx.x;
    if (i >= N) return;
    dinv[i] = rsqrtf((float)(cnt[i] + 1));   // +1 self-loop
}

// single-block exclusive scan over cnt[0..N) -> offsets[0..N]
__global__ __launch_bounds__(1024) void k_scan(const int* __restrict__ cnt,
                                               int* __restrict__ offsets, int N) {
    __shared__ int buf[1024];
    const int t = threadIdx.x;
    const int T = 1024;
    const int chunk = (N + T - 1) / T;
    const int lo = t * chunk;
    const int hi = (lo + chunk < N) ? lo + chunk : N;
    int s = 0;
    for (int i = lo; i < hi; ++i) s += cnt[i];
    buf[t] = s;
    __syncthreads();
    for (int off = 1; off < T; off <<= 1) {
        int v = (t >= off) ? buf[t - off] : 0;
        __syncthreads();
        buf[t] += v;
        __syncthreads();
    }
    int run = (t == 0) ? 0 : buf[t - 1];
    for (int i = lo; i < hi; ++i) { offsets[i] = run; run += cnt[i]; }
    if (t == T - 1) offsets[N] = buf[T - 1];
}

__global__ void k_scatter(const int* __restrict__ src, const int* __restrict__ dst, int E,
                          const int* __restrict__ offsets, int* __restrict__ cursor,
                          const float* __restrict__ dinv,
                          int* __restrict__ src_s, float* __restrict__ norm_s, int N) {
    int e = blockIdx.x * blockDim.x + threadIdx.x;
    if (e >= E) return;
    int d = dst[e], s = src[e];
    if (d < 0 || d >= N || s < 0 || s >= N) return;   // safety guard
    int p = offsets[d] + atomicAdd(&cursor[d], 1);
    src_s[p]  = s;
    norm_s[p] = dinv[s] * dinv[d];
}

// ---------------------------------------------------------------------------
// GEMM: Y[N][OUT] = X[N][128] @ W[128][OUT], fp32 vector ALU.
// BM=32 rows/block, 256 threads, each thread RPT rows x 4 cols of output.
// ---------------------------------------------------------------------------
template <int OUT>
__global__ __launch_bounds__(256) void k_gemm(const float* __restrict__ X,
                                              const float* __restrict__ W,
                                              float* __restrict__ Y, int N) {
    constexpr int K   = 128;
    constexpr int BM  = 32;
    constexpr int TXN = OUT / 4;                    // threads along columns
    constexpr int RPT = (BM * OUT) / (256 * 4);     // rows per thread (4 or 2)
    __shared__ float Ws[K * OUT];
    __shared__ float Xs[BM * K];
    const int t    = threadIdx.x;
    const int row0 = blockIdx.x * BM;

    for (int i = t * 4; i < K * OUT; i += 256 * 4)
        *(float4*)&Ws[i] = *(const float4*)&W[i];
    for (int i = t * 4; i < BM * K; i += 256 * 4) {
        int r = row0 + i / K;
        float4 v = make_float4(0.f, 0.f, 0.f, 0.f);
        if (r < N) v = *(const float4*)&X[(size_t)row0 * K + i];
        *(float4*)&Xs[i] = v;
    }
    __syncthreads();

    const int tx = t % TXN;
    const int ty = t / TXN;
    const int c0 = tx * 4;
    const int r0 = ty * RPT;

    float4 acc[RPT];
#pragma unroll
    for (int r = 0; r < RPT; ++r) acc[r] = make_float4(0.f, 0.f, 0.f, 0.f);

#pragma unroll 4
    for (int k4 = 0; k4 < K / 4; ++k4) {
        const float4 wv0 = *(const float4*)&Ws[(k4 * 4 + 0) * OUT + c0];
        const float4 wv1 = *(const float4*)&Ws[(k4 * 4 + 1) * OUT + c0];
        const float4 wv2 = *(const float4*)&Ws[(k4 * 4 + 2) * OUT + c0];
        const float4 wv3 = *(const float4*)&Ws[(k4 * 4 + 3) * OUT + c0];
#pragma unroll
        for (int r = 0; r < RPT; ++r) {
            const float4 xv = *(const float4*)&Xs[(r0 + r) * K + k4 * 4];
            acc[r].x += xv.x * wv0.x + xv.y * wv1.x + xv.z * wv2.x + xv.w * wv3.x;
            acc[r].y += xv.x * wv0.y + xv.y * wv1.y + xv.z * wv2.y + xv.w * wv3.y;
            acc[r].z += xv.x * wv0.z + xv.y * wv1.z + xv.z * wv2.z + xv.w * wv3.z;
            acc[r].w += xv.x * wv0.w + xv.y * wv1.w + xv.z * wv2.w + xv.w * wv3.w;
        }
    }

#pragma unroll
    for (int r = 0; r < RPT; ++r) {
        int row = row0 + r0 + r;
        if (row < N) *(float4*)&Y[(size_t)row * OUT + c0] = acc[r];
    }
}

// ---------------------------------------------------------------------------
// Aggregation, 128 feats: one wave per node, lane owns 2 adjacent feats.
// out[n] = relu( dinv[n]^2 * m[n] + sum_e norm[e]*m[src[e]] + b )
// ---------------------------------------------------------------------------
__global__ __launch_bounds__(256) void k_agg128(const float* __restrict__ M,
                                                const int* __restrict__ offsets,
                                                const int* __restrict__ srcs,
                                                const float* __restrict__ norms,
                                                const float* __restrict__ dinv,
                                                const float* __restrict__ bias,
                                                float* __restrict__ Y, int N) {
    const int lane = threadIdx.x & (WAVE - 1);
    const int node = blockIdx.x * 4 + (threadIdx.x >> 6);
    if (node >= N) return;
    const float di = dinv[node];
    const float w0 = di * di;
    float2 mv = *(const float2*)&M[(size_t)node * 128 + lane * 2];
    float a0 = mv.x * w0, a1 = mv.y * w0;
    const int e0 = offsets[node], e1 = offsets[node + 1];
    for (int e = e0; e < e1; ++e) {
        const int   s = srcs[e];
        const float w = norms[e];
        float2 v = *(const float2*)&M[(size_t)s * 128 + lane * 2];
        a0 += v.x * w;
        a1 += v.y * w;
    }
    float2 b = *(const float2*)&bias[lane * 2];
    a0 = fmaxf(a0 + b.x, 0.f);
    a1 = fmaxf(a1 + b.y, 0.f);
    *(float2*)&Y[(size_t)node * 128 + lane * 2] = make_float2(a0, a1);
}

// ---------------------------------------------------------------------------
// Final aggregation, 64 feats: lane == feature; fused bias + log_softmax.
// ---------------------------------------------------------------------------
__global__ __launch_bounds__(256) void k_agg64_lsm(const float* __restrict__ M,
                                                   const int* __restrict__ offsets,
                                                   const int* __restrict__ srcs,
                                                   const float* __restrict__ norms,
                                                   const float* __restrict__ dinv,
                                                   const float* __restrict__ bias,
                                                   float* __restrict__ Y, int N) {
    const int lane = threadIdx.x & (WAVE - 1);
    const int node = blockIdx.x * 4 + (threadIdx.x >> 6);
    if (node >= N) return;
    const float di = dinv[node];
    float acc = M[(size_t)node * 64 + lane] * di * di;
    const int e0 = offsets[node], e1 = offsets[node + 1];
    for (int e = e0; e < e1; ++e)
        acc += M[(size_t)srcs[e] * 64 + lane] * norms[e];
    float v = acc + bias[lane];
    float m = v;
#pragma unroll
    for (int o = 32; o > 0; o >>= 1) m = fmaxf(m, __shfl_xor(m, o));
    float s = __expf(v - m);
    // use accurate expf to stay close to numpy
    s = expf(v - m);
#pragma unroll
    for (int o = 32; o > 0; o >>= 1) s += __shfl_xor(s, o);
    Y[(size_t)node * 64 + lane] = v - m - logf(s);
}

// ---------------------------------------------------------------------------

extern "C" void kernel_launch(void* const* d_in, const int* in_sizes, int n_in,
                              void* d_out, int out_size, void* d_ws, size_t ws_size,
                              hipStream_t stream) {
    const float* x  = (const float*)d_in[0];
    const int*   ei = (const int*)d_in[1];      // int32 per harness convention
    const float* W1 = (const float*)d_in[2];
    const float* b1 = (const float*)d_in[3];
    const float* W2 = (const float*)d_in[4];
    const float* b2 = (const float*)d_in[5];
    const float* Wf = (const float*)d_in[6];
    const float* bf = (const float*)d_in[7];
    float* out = (float*)d_out;

    const int N = in_sizes[0] / 128;
    const int E = in_sizes[1] / 2;
    const int* src = ei;
    const int* dst = ei + E;

    // workspace carve-up (256B aligned)
    char* ws = (char*)d_ws;
    auto alloc = [&](size_t bytes) -> void* {
        void* p = ws;
        ws += (bytes + 255) & ~(size_t)255;
        return p;
    };
    int*   cnt    = (int*)alloc((size_t)N * 4);
    int*   cursor = (int*)alloc((size_t)N * 4);
    int*   offs   = (int*)alloc((size_t)(N + 1) * 4);
    float* dinv   = (float*)alloc((size_t)N * 4);
    int*   src_s  = (int*)alloc((size_t)E * 4);
    float* norm_s = (float*)alloc((size_t)E * 4);
    float* tmp1   = (float*)alloc((size_t)N * 128 * 4);
    float* tmp2   = (float*)alloc((size_t)N * 128 * 4);

    hipMemsetAsync(cnt, 0, (size_t)N * 4, stream);
    hipMemsetAsync(cursor, 0, (size_t)N * 4, stream);

    const int TB = 256;
    k_count<<<(E + TB - 1) / TB, TB, 0, stream>>>(dst, E, cnt, N);
    k_dinv<<<(N + TB - 1) / TB, TB, 0, stream>>>(cnt, dinv, N);
    k_scan<<<1, 1024, 0, stream>>>(cnt, offs, N);
    k_scatter<<<(E + TB - 1) / TB, TB, 0, stream>>>(src, dst, E, offs, cursor,
                                                    dinv, src_s, norm_s, N);

    const int gemm_grid = (N + 31) / 32;
    const int agg_grid  = (N + 3) / 4;

    // layer 1
    k_gemm<128><<<gemm_grid, 256, 0, stream>>>(x, W1, tmp1, N);
    k_agg128<<<agg_grid, 256, 0, stream>>>(tmp1, offs, src_s, norm_s, dinv, b1, tmp2, N);
    // layer 2
    k_gemm<128><<<gemm_grid, 256, 0, stream>>>(tmp2, W2, tmp1, N);
    k_agg128<<<agg_grid, 256, 0, stream>>>(tmp1, offs, src_s, norm_s, dinv, b2, tmp2, N);
    // layer 3 + log_softmax
    k_gemm<64><<<gemm_grid, 256, 0, stream>>>(tmp2, Wf, tmp1, N);
    k_agg64_lsm<<<agg_grid, 256, 0, stream>>>(tmp1, offs, src_s, norm_s, dinv, bf, out, N);
}

// Round 2
// 333.509 us; speedup vs baseline: 1.3848x; 1.3848x over previous
//
#include <hip/hip_runtime.h>
#include <hip/hip_bf16.h>
#include <cstdint>
#include <cstddef>

// ---------------------------------------------------------------------------
// 3-layer GCN: h1 = relu(A @ (x@W1) + b1); h2 = relu(A @ (h1@W2) + b2);
// out = log_softmax(A @ (h2@Wf) + bf)
// A = D^-1/2 (Adj + I) D^-1/2  (symmetric GCN norm with self-loops)
//
// CSR-by-dst built per call: count -> hierarchical scan (3 small kernels,
// replaces the 78us single-block scan) -> scatter. Per layer: fp32 LDS-tiled
// GEMM (no fp32 MFMA on CDNA4) + wave-per-node gather aggregation.
// ---------------------------------------------------------------------------

#define WAVE 64

__global__ void k_count(const int* __restrict__ dst, int E, int* __restrict__ cnt, int N) {
    int e = blockIdx.x * blockDim.x + threadIdx.x;
    if (e >= E) return;
    int d = dst[e];
    if (d >= 0 && d < N) atomicAdd(&cnt[d], 1);
}

// --- hierarchical exclusive scan over cnt[0..N) -> offs[0..N] --------------
// pass 1: per-block (1024 elems) sums
__global__ __launch_bounds__(256) void k_blocksum(const int* __restrict__ cnt, int N,
                                                  int* __restrict__ partial) {
    const int t  = threadIdx.x;
    const int b  = blockIdx.x;
    const int i0 = b * 1024 + t * 4;
    int s = 0;
#pragma unroll
    for (int j = 0; j < 4; ++j) {
        int i = i0 + j;
        if (i < N) s += cnt[i];
    }
#pragma unroll
    for (int o = 32; o > 0; o >>= 1) s += __shfl_xor(s, o);
    __shared__ int ws[4];
    if ((t & 63) == 0) ws[t >> 6] = s;
    __syncthreads();
    if (t == 0) partial[b] = ws[0] + ws[1] + ws[2] + ws[3];
}

// pass 2: single wave scans the (<=64) partials; writes block bases + total
__global__ __launch_bounds__(64) void k_scanpartials(int* __restrict__ partial, int numB,
                                                     int* __restrict__ base,
                                                     int* __restrict__ offs, int N) {
    const int t = threadIdx.x;
    int v = (t < numB) ? partial[t] : 0;
    int incl = v;
#pragma unroll
    for (int o = 1; o < 64; o <<= 1) {
        int u = __shfl_up(incl, o);
        if (t >= o) incl += u;
    }
    if (t < numB) base[t] = incl - v;   // exclusive
    if (t == 63) offs[N] = incl;        // grand total
}

// pass 3: local scan + base; also emits dinv and zeroes cursor
__global__ __launch_bounds__(256) void k_blockscan(const int* __restrict__ cnt, int N,
                                                   const int* __restrict__ base,
                                                   int* __restrict__ offs,
                                                   float* __restrict__ dinv,
                                                   int* __restrict__ cursor) {
    const int t  = threadIdx.x;
    const int b  = blockIdx.x;
    const int i0 = b * 1024 + t * 4;
    int c[4];
    int tsum = 0;
#pragma unroll
    for (int j = 0; j < 4; ++j) {
        int i = i0 + j;
        c[j] = (i < N) ? cnt[i] : 0;
        tsum += c[j];
    }
    int incl = tsum;
#pragma unroll
    for (int o = 1; o < 64; o <<= 1) {
        int u = __shfl_up(incl, o);
        if ((t & 63) >= o) incl += u;
    }
    __shared__ int ws[4];
    const int wid = t >> 6;
    if ((t & 63) == 63) ws[wid] = incl;
    __syncthreads();
    int wbase = 0;
    for (int w = 0; w < wid; ++w) wbase += ws[w];
    int run = base[b] + wbase + (incl - tsum);   // exclusive start for this thread
#pragma unroll
    for (int j = 0; j < 4; ++j) {
        int i = i0 + j;
        if (i < N) {
            offs[i]   = run;
            run      += c[j];
            dinv[i]   = rsqrtf((float)(c[j] + 1));   // +1 self-loop
            cursor[i] = 0;
        }
    }
}

__global__ void k_scatter(const int* __restrict__ src, const int* __restrict__ dst, int E,
                          const int* __restrict__ offsets, int* __restrict__ cursor,
                          const float* __restrict__ dinv,
                          int* __restrict__ src_s, float* __restrict__ norm_s, int N) {
    int e = blockIdx.x * blockDim.x + threadIdx.x;
    if (e >= E) return;
    int d = dst[e], s = src[e];
    if (d < 0 || d >= N || s < 0 || s >= N) return;   // safety guard
    int p = offsets[d] + atomicAdd(&cursor[d], 1);
    src_s[p]  = s;
    norm_s[p] = dinv[s] * dinv[d];
}

// ---------------------------------------------------------------------------
// GEMM: Y[N][OUT] = X[N][128] @ W[128][OUT], fp32 vector ALU.
// BM=32 rows/block, 256 threads, each thread RPT rows x 4 cols of output.
// ---------------------------------------------------------------------------
template <int OUT>
__global__ __launch_bounds__(256) void k_gemm(const float* __restrict__ X,
                                              const float* __restrict__ W,
                                              float* __restrict__ Y, int N) {
    constexpr int K   = 128;
    constexpr int BM  = 32;
    constexpr int TXN = OUT / 4;                    // threads along columns
    constexpr int RPT = (BM * OUT) / (256 * 4);     // rows per thread (4 or 2)
    __shared__ float Ws[K * OUT];
    __shared__ float Xs[BM * K];
    const int t    = threadIdx.x;
    const int row0 = blockIdx.x * BM;

    for (int i = t * 4; i < K * OUT; i += 256 * 4)
        *(float4*)&Ws[i] = *(const float4*)&W[i];
    for (int i = t * 4; i < BM * K; i += 256 * 4) {
        int r = row0 + i / K;
        float4 v = make_float4(0.f, 0.f, 0.f, 0.f);
        if (r < N) v = *(const float4*)&X[(size_t)row0 * K + i];
        *(float4*)&Xs[i] = v;
    }
    __syncthreads();

    const int tx = t % TXN;
    const int ty = t / TXN;
    const int c0 = tx * 4;
    const int r0 = ty * RPT;

    float4 acc[RPT];
#pragma unroll
    for (int r = 0; r < RPT; ++r) acc[r] = make_float4(0.f, 0.f, 0.f, 0.f);

#pragma unroll 4
    for (int k4 = 0; k4 < K / 4; ++k4) {
        const float4 wv0 = *(const float4*)&Ws[(k4 * 4 + 0) * OUT + c0];
        const float4 wv1 = *(const float4*)&Ws[(k4 * 4 + 1) * OUT + c0];
        const float4 wv2 = *(const float4*)&Ws[(k4 * 4 + 2) * OUT + c0];
        const float4 wv3 = *(const float4*)&Ws[(k4 * 4 + 3) * OUT + c0];
#pragma unroll
        for (int r = 0; r < RPT; ++r) {
            const float4 xv = *(const float4*)&Xs[(r0 + r) * K + k4 * 4];
            acc[r].x += xv.x * wv0.x + xv.y * wv1.x + xv.z * wv2.x + xv.w * wv3.x;
            acc[r].y += xv.x * wv0.y + xv.y * wv1.y + xv.z * wv2.y + xv.w * wv3.y;
            acc[r].z += xv.x * wv0.z + xv.y * wv1.z + xv.z * wv2.z + xv.w * wv3.z;
            acc[r].w += xv.x * wv0.w + xv.y * wv1.w + xv.z * wv2.w + xv.w * wv3.w;
        }
    }

#pragma unroll
    for (int r = 0; r < RPT; ++r) {
        int row = row0 + r0 + r;
        if (row < N) *(float4*)&Y[(size_t)row * OUT + c0] = acc[r];
    }
}

// ---------------------------------------------------------------------------
// Aggregation, 128 feats: one wave per node, lane owns 2 adjacent feats.
// out[n] = relu( dinv[n]^2 * m[n] + sum_e norm[e]*m[src[e]] + b )
// Gather loop unrolled x2 so two independent row-reads are in flight.
// ---------------------------------------------------------------------------
__global__ __launch_bounds__(256) void k_agg128(const float* __restrict__ M,
                                                const int* __restrict__ offsets,
                                                const int* __restrict__ srcs,
                                                const float* __restrict__ norms,
                                                const float* __restrict__ dinv,
                                                const float* __restrict__ bias,
                                                float* __restrict__ Y, int N) {
    const int lane = threadIdx.x & (WAVE - 1);
    const int node = blockIdx.x * 4 + (threadIdx.x >> 6);
    if (node >= N) return;
    const float di = dinv[node];
    const float w0 = di * di;
    float2 mv = *(const float2*)&M[(size_t)node * 128 + lane * 2];
    float a0 = mv.x * w0, a1 = mv.y * w0;
    const int e0 = offsets[node], e1 = offsets[node + 1];
    int e = e0;
    for (; e + 1 < e1; e += 2) {
        const int   s0 = srcs[e],  s1 = srcs[e + 1];
        const float u0 = norms[e], u1 = norms[e + 1];
        float2 v0 = *(const float2*)&M[(size_t)s0 * 128 + lane * 2];
        float2 v1 = *(const float2*)&M[(size_t)s1 * 128 + lane * 2];
        a0 += v0.x * u0 + v1.x * u1;
        a1 += v0.y * u0 + v1.y * u1;
    }
    if (e < e1) {
        const int   s = srcs[e];
        const float u = norms[e];
        float2 v = *(const float2*)&M[(size_t)s * 128 + lane * 2];
        a0 += v.x * u;
        a1 += v.y * u;
    }
    float2 b = *(const float2*)&bias[lane * 2];
    a0 = fmaxf(a0 + b.x, 0.f);
    a1 = fmaxf(a1 + b.y, 0.f);
    *(float2*)&Y[(size_t)node * 128 + lane * 2] = make_float2(a0, a1);
}

// ---------------------------------------------------------------------------
// Final aggregation, 64 feats: lane == feature; fused bias + log_softmax.
// ---------------------------------------------------------------------------
__global__ __launch_bounds__(256) void k_agg64_lsm(const float* __restrict__ M,
                                                   const int* __restrict__ offsets,
                                                   const int* __restrict__ srcs,
                                                   const float* __restrict__ norms,
                                                   const float* __restrict__ dinv,
                                                   const float* __restrict__ bias,
                                                   float* __restrict__ Y, int N) {
    const int lane = threadIdx.x & (WAVE - 1);
    const int node = blockIdx.x * 4 + (threadIdx.x >> 6);
    if (node >= N) return;
    const float di = dinv[node];
    float acc = M[(size_t)node * 64 + lane] * di * di;
    const int e0 = offsets[node], e1 = offsets[node + 1];
    int e = e0;
    for (; e + 1 < e1; e += 2) {
        const int   s0 = srcs[e],  s1 = srcs[e + 1];
        const float u0 = norms[e], u1 = norms[e + 1];
        acc += M[(size_t)s0 * 64 + lane] * u0 + M[(size_t)s1 * 64 + lane] * u1;
    }
    if (e < e1)
        acc += M[(size_t)srcs[e] * 64 + lane] * norms[e];
    float v = acc + bias[lane];
    float m = v;
#pragma unroll
    for (int o = 32; o > 0; o >>= 1) m = fmaxf(m, __shfl_xor(m, o));
    float s = expf(v - m);
#pragma unroll
    for (int o = 32; o > 0; o >>= 1) s += __shfl_xor(s, o);
    Y[(size_t)node * 64 + lane] = v - m - logf(s);
}

// ---------------------------------------------------------------------------

extern "C" void kernel_launch(void* const* d_in, const int* in_sizes, int n_in,
                              void* d_out, int out_size, void* d_ws, size_t ws_size,
                              hipStream_t stream) {
    const float* x  = (const float*)d_in[0];
    const int*   ei = (const int*)d_in[1];      // int32 per harness convention
    const float* W1 = (const float*)d_in[2];
    const float* b1 = (const float*)d_in[3];
    const float* W2 = (const float*)d_in[4];
    const float* b2 = (const float*)d_in[5];
    const float* Wf = (const float*)d_in[6];
    const float* bf = (const float*)d_in[7];
    float* out = (float*)d_out;

    const int N = in_sizes[0] / 128;
    const int E = in_sizes[1] / 2;
    const int* src = ei;
    const int* dst = ei + E;

    // workspace carve-up (256B aligned)
    char* ws = (char*)d_ws;
    auto alloc = [&](size_t bytes) -> void* {
        void* p = ws;
        ws += (bytes + 255) & ~(size_t)255;
        return p;
    };
    const int numB = (N + 1023) / 1024;
    int*   cnt    = (int*)alloc((size_t)N * 4);
    int*   cursor = (int*)alloc((size_t)N * 4);
    int*   offs   = (int*)alloc((size_t)(N + 1) * 4);
    float* dinv   = (float*)alloc((size_t)N * 4);
    int*   part   = (int*)alloc((size_t)numB * 4);
    int*   pbase  = (int*)alloc((size_t)numB * 4);
    int*   src_s  = (int*)alloc((size_t)E * 4);
    float* norm_s = (float*)alloc((size_t)E * 4);
    float* tmp1   = (float*)alloc((size_t)N * 128 * 4);
    float* tmp2   = (float*)alloc((size_t)N * 128 * 4);

    hipMemsetAsync(cnt, 0, (size_t)N * 4, stream);

    const int TB = 256;
    k_count<<<(E + TB - 1) / TB, TB, 0, stream>>>(dst, E, cnt, N);
    k_blocksum<<<numB, 256, 0, stream>>>(cnt, N, part);
    k_scanpartials<<<1, 64, 0, stream>>>(part, numB, pbase, offs, N);
    k_blockscan<<<numB, 256, 0, stream>>>(cnt, N, pbase, offs, dinv, cursor);
    k_scatter<<<(E + TB - 1) / TB, TB, 0, stream>>>(src, dst, E, offs, cursor,
                                                    dinv, src_s, norm_s, N);

    const int gemm_grid = (N + 31) / 32;
    const int agg_grid  = (N + 3) / 4;

    // layer 1
    k_gemm<128><<<gemm_grid, 256, 0, stream>>>(x, W1, tmp1, N);
    k_agg128<<<agg_grid, 256, 0, stream>>>(tmp1, offs, src_s, norm_s, dinv, b1, tmp2, N);
    // layer 2
    k_gemm<128><<<gemm_grid, 256, 0, stream>>>(tmp2, W2, tmp1, N);
    k_agg128<<<agg_grid, 256, 0, stream>>>(tmp1, offs, src_s, norm_s, dinv, b2, tmp2, N);
    // layer 3 + log_softmax
    k_gemm<64><<<gemm_grid, 256, 0, stream>>>(tmp2, Wf, tmp1, N);
    k_agg64_lsm<<<agg_grid, 256, 0, stream>>>(tmp1, offs, src_s, norm_s, dinv, bf, out, N);
}

// Round 3
// 259.878 us; speedup vs baseline: 1.7772x; 1.2833x over previous
//
#include <hip/hip_runtime.h>
#include <cstdint>
#include <cstddef>

// ---------------------------------------------------------------------------
// 3-layer GCN, fp16 message pipeline:
//   m' = (h @ W) * dinv[row]      (MFMA f16 GEMM, fp32 accum, fp16 out)
//   h' = relu(dinv[n] * (m'[n] + sum_{e->n} m'[src]) + b)   (fp16 out)
// final layer: logits fp32 + log_softmax.
// CSR-by-dst built per call (count -> hierarchical scan -> scatter).
// ---------------------------------------------------------------------------

#define WAVE 64
typedef _Float16 f16;
typedef f16  f16x2 __attribute__((ext_vector_type(2)));
typedef f16  f16x4 __attribute__((ext_vector_type(4)));
typedef f16  f16x8 __attribute__((ext_vector_type(8)));
typedef float f32x4 __attribute__((ext_vector_type(4)));

// ------------------------------ setup --------------------------------------

__global__ void k_count(const int* __restrict__ dst, int E, int* __restrict__ cnt, int N) {
    int e = blockIdx.x * blockDim.x + threadIdx.x;
    if (e >= E) return;
    int d = dst[e];
    if (d >= 0 && d < N) atomicAdd(&cnt[d], 1);
}

__global__ __launch_bounds__(256) void k_blocksum(const int* __restrict__ cnt, int N,
                                                  int* __restrict__ partial) {
    const int t  = threadIdx.x;
    const int b  = blockIdx.x;
    const int i0 = b * 1024 + t * 4;
    int s = 0;
#pragma unroll
    for (int j = 0; j < 4; ++j) {
        int i = i0 + j;
        if (i < N) s += cnt[i];
    }
#pragma unroll
    for (int o = 32; o > 0; o >>= 1) s += __shfl_xor(s, o);
    __shared__ int ws[4];
    if ((t & 63) == 0) ws[t >> 6] = s;
    __syncthreads();
    if (t == 0) partial[b] = ws[0] + ws[1] + ws[2] + ws[3];
}

__global__ __launch_bounds__(64) void k_scanpartials(int* __restrict__ partial, int numB,
                                                     int* __restrict__ base,
                                                     int* __restrict__ offs, int N) {
    const int t = threadIdx.x;
    int v = (t < numB) ? partial[t] : 0;
    int incl = v;
#pragma unroll
    for (int o = 1; o < 64; o <<= 1) {
        int u = __shfl_up(incl, o);
        if (t >= o) incl += u;
    }
    if (t < numB) base[t] = incl - v;
    if (t == 63) offs[N] = incl;
}

__global__ __launch_bounds__(256) void k_blockscan(const int* __restrict__ cnt, int N,
                                                   const int* __restrict__ base,
                                                   int* __restrict__ offs,
                                                   float* __restrict__ dinv,
                                                   int* __restrict__ cursor) {
    const int t  = threadIdx.x;
    const int b  = blockIdx.x;
    const int i0 = b * 1024 + t * 4;
    int c[4];
    int tsum = 0;
#pragma unroll
    for (int j = 0; j < 4; ++j) {
        int i = i0 + j;
        c[j] = (i < N) ? cnt[i] : 0;
        tsum += c[j];
    }
    int incl = tsum;
#pragma unroll
    for (int o = 1; o < 64; o <<= 1) {
        int u = __shfl_up(incl, o);
        if ((t & 63) >= o) incl += u;
    }
    __shared__ int ws[4];
    const int wid = t >> 6;
    if ((t & 63) == 63) ws[wid] = incl;
    __syncthreads();
    int wbase = 0;
    for (int w = 0; w < wid; ++w) wbase += ws[w];
    int run = base[b] + wbase + (incl - tsum);
#pragma unroll
    for (int j = 0; j < 4; ++j) {
        int i = i0 + j;
        if (i < N) {
            offs[i]   = run;
            run      += c[j];
            dinv[i]   = rsqrtf((float)(c[j] + 1));   // +1 self-loop
            cursor[i] = 0;
        }
    }
}

__global__ void k_scatter(const int* __restrict__ src, const int* __restrict__ dst, int E,
                          const int* __restrict__ offsets, int* __restrict__ cursor,
                          int* __restrict__ src_s, int N) {
    int e = blockIdx.x * blockDim.x + threadIdx.x;
    if (e >= E) return;
    int d = dst[e], s = src[e];
    if (d < 0 || d >= N || s < 0 || s >= N) return;
    int p = offsets[d] + atomicAdd(&cursor[d], 1);
    src_s[p] = s;
}

// --------------------------- fp16 conversions ------------------------------

__global__ void k_cvt_x(const float* __restrict__ X, f16* __restrict__ X16, int total4) {
    int i = blockIdx.x * blockDim.x + threadIdx.x;
    if (i >= total4) return;
    float4 v = *(const float4*)&X[(size_t)i * 4];
    f16x4 o = { (f16)v.x, (f16)v.y, (f16)v.z, (f16)v.w };
    *(f16x4*)&X16[(size_t)i * 4] = o;
}

// Wt16[n][k] = (f16) W[k][n]   (n in [0,OUT), k in [0,128))
template <int OUT>
__global__ void k_cvt_wt(const float* __restrict__ W, f16* __restrict__ Wt) {
    int i = blockIdx.x * 256 + threadIdx.x;
    if (i >= OUT * 128) return;
    int n = i >> 7, k = i & 127;
    Wt[i] = (f16)W[k * OUT + n];
}

// ------------------------------ MFMA GEMM ----------------------------------
// M16[m][n] = ( A16[m][:] @ W[:][n] ) * dinv[m],  K=128 fixed.
// Block: 256 threads (4 waves), 64 rows; wave owns OUT/4 columns.
// A-frag: m = lane&15, k = 8*(lane>>4)+e (global 16B loads)
// B-frag: n = lane&15, k = 8*(lane>>4)+e (LDS, XOR-swizzled transposed W)
// D: col = lane&15, row = 4*(lane>>4)+r
template <int OUT>
__global__ __launch_bounds__(256) void k_gemm_mfma(const f16* __restrict__ A,
                                                   const f16* __restrict__ Wt,
                                                   const float* __restrict__ dinv,
                                                   f16* __restrict__ M,
                                                   int N) {
    constexpr int K  = 128;
    constexpr int CW = OUT / 64;          // col-tiles per wave (2 or 1)
    __shared__ char smem[OUT * K * 2];    // W (swizzled), then reused as out-tile
    __shared__ float dl[64];

    const int t    = threadIdx.x;
    const int w    = t >> 6;
    const int lane = t & 63;
    const int ln   = lane & 15;
    const int lh   = lane >> 4;
    const int row0 = blockIdx.x * 64;

    // stage transposed W into LDS, XOR-swizzled per 16B chunk
    {
        constexpr int NCH = OUT * 16;     // 16 x 16B chunks per 256B row
        for (int j = t; j < NCH; j += 256) {
            int n = j >> 4;
            uint32_t byte = (uint32_t)j * 16;
            uint32_t swz  = byte ^ (uint32_t)((n & 7) << 4);
            *(f16x8*)(smem + swz) = *(const f16x8*)&Wt[(size_t)j * 8];
        }
        if (t < 64) {
            int r = row0 + t;
            dl[t] = dinv[r < N ? r : (N - 1)];
        }
    }
    __syncthreads();

    // hoist B fragments to registers
    f16x8 bfr[CW][4];
    const int c0 = w * CW;
#pragma unroll
    for (int c = 0; c < CW; ++c) {
        int n = (c0 + c) * 16 + ln;
#pragma unroll
        for (int q = 0; q < 4; ++q) {
            uint32_t byte = (uint32_t)(n * 256 + q * 64 + lh * 16);
            uint32_t swz  = byte ^ (uint32_t)((n & 7) << 4);
            bfr[c][q] = *(const f16x8*)(smem + swz);
        }
    }
    __syncthreads();   // all waves done reading W; smem may be overwritten below

    f32x4 acc[4][CW];
#pragma unroll
    for (int s = 0; s < 4; ++s)
#pragma unroll
        for (int c = 0; c < CW; ++c)
            acc[s][c] = f32x4{0.f, 0.f, 0.f, 0.f};

#pragma unroll
    for (int s = 0; s < 4; ++s) {
        int m = row0 + s * 16 + ln;
        const f16* arow = A + (size_t)(m < N ? m : (N - 1)) * K;
#pragma unroll
        for (int q = 0; q < 4; ++q) {
            f16x8 a = *(const f16x8*)&arow[q * 32 + lh * 8];
#pragma unroll
            for (int c = 0; c < CW; ++c)
                acc[s][c] = __builtin_amdgcn_mfma_f32_16x16x32_f16(a, bfr[c][q], acc[s][c], 0, 0, 0);
        }
    }

    // epilogue: scale by dinv[row], fp16, bounce through LDS for coalesced store
    f16* ot = (f16*)smem;
#pragma unroll
    for (int s = 0; s < 4; ++s) {
#pragma unroll
        for (int c = 0; c < CW; ++c) {
            int col = (c0 + c) * 16 + ln;
#pragma unroll
            for (int r = 0; r < 4; ++r) {
                int rl = s * 16 + lh * 4 + r;
                ot[rl * OUT + col] = (f16)(acc[s][c][r] * dl[rl]);
            }
        }
    }
    __syncthreads();

    constexpr int CPR = OUT / 8;          // 16B chunks per row
    for (int j = t; j < 64 * CPR; j += 256) {
        int rl = j / CPR;
        if (row0 + rl < N)
            *(f16x8*)&M[(size_t)(row0 + rl) * OUT + (j % CPR) * 8] =
                *(const f16x8*)&ot[(size_t)j * 8];
    }
}

// ------------------------------ aggregation --------------------------------
// h'[n] = relu( dinv[n] * (m'[n] + sum m'[src]) + b ),  fp16 in/out, fp32 accum
__global__ __launch_bounds__(256) void k_agg128_f16(const f16* __restrict__ M16,
                                                    const int* __restrict__ offs,
                                                    const int* __restrict__ srcs,
                                                    const float* __restrict__ dinv,
                                                    const float* __restrict__ bias,
                                                    f16* __restrict__ H16, int N) {
    const int lane = threadIdx.x & (WAVE - 1);
    const int node = blockIdx.x * 4 + (threadIdx.x >> 6);
    if (node >= N) return;
    f16x2 mv = *(const f16x2*)&M16[(size_t)node * 128 + lane * 2];
    float a0 = (float)mv.x, a1 = (float)mv.y;
    const int e0 = offs[node], e1 = offs[node + 1];
    int e = e0;
    for (; e + 1 < e1; e += 2) {
        int s0 = srcs[e], s1 = srcs[e + 1];
        f16x2 v0 = *(const f16x2*)&M16[(size_t)s0 * 128 + lane * 2];
        f16x2 v1 = *(const f16x2*)&M16[(size_t)s1 * 128 + lane * 2];
        a0 += (float)v0.x + (float)v1.x;
        a1 += (float)v0.y + (float)v1.y;
    }
    if (e < e1) {
        f16x2 v = *(const f16x2*)&M16[(size_t)srcs[e] * 128 + lane * 2];
        a0 += (float)v.x;
        a1 += (float)v.y;
    }
    const float dn = dinv[node];
    float2 b = *(const float2*)&bias[lane * 2];
    float r0 = fmaxf(a0 * dn + b.x, 0.f);
    float r1 = fmaxf(a1 * dn + b.y, 0.f);
    f16x2 o = { (f16)r0, (f16)r1 };
    *(f16x2*)&H16[(size_t)node * 128 + lane * 2] = o;
}

// final: logits fp32 + fused log_softmax; lane == class
__global__ __launch_bounds__(256) void k_agg64_lsm(const f16* __restrict__ M16,
                                                   const int* __restrict__ offs,
                                                   const int* __restrict__ srcs,
                                                   const float* __restrict__ dinv,
                                                   const float* __restrict__ bias,
                                                   float* __restrict__ Y, int N) {
    const int lane = threadIdx.x & (WAVE - 1);
    const int node = blockIdx.x * 4 + (threadIdx.x >> 6);
    if (node >= N) return;
    float acc = (float)M16[(size_t)node * 64 + lane];
    const int e0 = offs[node], e1 = offs[node + 1];
    int e = e0;
    for (; e + 1 < e1; e += 2) {
        acc += (float)M16[(size_t)srcs[e] * 64 + lane]
             + (float)M16[(size_t)srcs[e + 1] * 64 + lane];
    }
    if (e < e1) acc += (float)M16[(size_t)srcs[e] * 64 + lane];
    float v = acc * dinv[node] + bias[lane];
    float m = v;
#pragma unroll
    for (int o = 32; o > 0; o >>= 1) m = fmaxf(m, __shfl_xor(m, o));
    float s = expf(v - m);
#pragma unroll
    for (int o = 32; o > 0; o >>= 1) s += __shfl_xor(s, o);
    Y[(size_t)node * 64 + lane] = v - m - logf(s);
}

// ---------------------------------------------------------------------------

extern "C" void kernel_launch(void* const* d_in, const int* in_sizes, int n_in,
                              void* d_out, int out_size, void* d_ws, size_t ws_size,
                              hipStream_t stream) {
    const float* x  = (const float*)d_in[0];
    const int*   ei = (const int*)d_in[1];
    const float* W1 = (const float*)d_in[2];
    const float* b1 = (const float*)d_in[3];
    const float* W2 = (const float*)d_in[4];
    const float* b2 = (const float*)d_in[5];
    const float* Wf = (const float*)d_in[6];
    const float* bf = (const float*)d_in[7];
    float* out = (float*)d_out;

    const int N = in_sizes[0] / 128;
    const int E = in_sizes[1] / 2;
    const int* src = ei;
    const int* dst = ei + E;

    char* ws = (char*)d_ws;
    auto alloc = [&](size_t bytes) -> void* {
        void* p = ws;
        ws += (bytes + 255) & ~(size_t)255;
        return p;
    };
    const int numB = (N + 1023) / 1024;
    int*   cnt    = (int*)alloc((size_t)N * 4);
    int*   cursor = (int*)alloc((size_t)N * 4);
    int*   offs   = (int*)alloc((size_t)(N + 1) * 4);
    float* dinv   = (float*)alloc((size_t)N * 4);
    int*   part   = (int*)alloc((size_t)numB * 4);
    int*   pbase  = (int*)alloc((size_t)numB * 4);
    int*   src_s  = (int*)alloc((size_t)E * 4);
    f16*   x16    = (f16*)alloc((size_t)N * 128 * 2);
    f16*   m16    = (f16*)alloc((size_t)N * 128 * 2);
    f16*   h16    = (f16*)alloc((size_t)N * 128 * 2);
    f16*   Wt1    = (f16*)alloc(128 * 128 * 2);
    f16*   Wt2    = (f16*)alloc(128 * 128 * 2);
    f16*   Wtf    = (f16*)alloc(128 * 64 * 2);

    hipMemsetAsync(cnt, 0, (size_t)N * 4, stream);

    const int TB = 256;
    k_count<<<(E + TB - 1) / TB, TB, 0, stream>>>(dst, E, cnt, N);
    k_blocksum<<<numB, 256, 0, stream>>>(cnt, N, part);
    k_scanpartials<<<1, 64, 0, stream>>>(part, numB, pbase, offs, N);
    k_blockscan<<<numB, 256, 0, stream>>>(cnt, N, pbase, offs, dinv, cursor);
    k_scatter<<<(E + TB - 1) / TB, TB, 0, stream>>>(src, dst, E, offs, cursor, src_s, N);

    const int total4 = N * 32;
    k_cvt_x<<<(total4 + TB - 1) / TB, TB, 0, stream>>>(x, x16, total4);
    k_cvt_wt<128><<<64, 256, 0, stream>>>(W1, Wt1);
    k_cvt_wt<128><<<64, 256, 0, stream>>>(W2, Wt2);
    k_cvt_wt<64><<<32, 256, 0, stream>>>(Wf, Wtf);

    const int gemm_grid = (N + 63) / 64;
    const int agg_grid  = (N + 3) / 4;

    k_gemm_mfma<128><<<gemm_grid, 256, 0, stream>>>(x16, Wt1, dinv, m16, N);
    k_agg128_f16<<<agg_grid, 256, 0, stream>>>(m16, offs, src_s, dinv, b1, h16, N);

    k_gemm_mfma<128><<<gemm_grid, 256, 0, stream>>>(h16, Wt2, dinv, m16, N);
    k_agg128_f16<<<agg_grid, 256, 0, stream>>>(m16, offs, src_s, dinv, b2, h16, N);

    k_gemm_mfma<64><<<gemm_grid, 256, 0, stream>>>(h16, Wtf, dinv, m16, N);
    k_agg64_lsm<<<agg_grid, 256, 0, stream>>>(m16, offs, src_s, dinv, bf, out, N);
}

// Round 4
// 225.406 us; speedup vs baseline: 2.0490x; 1.1529x over previous
//
#include <hip/hip_runtime.h>
#include <cstdint>
#include <cstddef>

// ---------------------------------------------------------------------------
// 3-layer GCN, fp16 message pipeline:
//   m' = (h @ W) * dinv[row]      (MFMA f16 GEMM, fp32 accum, fp16 out)
//   h' = relu(dinv[n] * (m'[n] + sum_{e->n} m'[src]) + b)   (fp16 out)
// final layer: logits fp32 + log_softmax.
// CSR-by-dst built per call (count -> hierarchical scan -> scatter).
// Aggregation is latency-bound: half-wave per edge + x4 unroll = 8 edges
// (4 vmem) in flight per wave (was 2).
// ---------------------------------------------------------------------------

#define WAVE 64
typedef _Float16 f16;
typedef f16  f16x2 __attribute__((ext_vector_type(2)));
typedef f16  f16x4 __attribute__((ext_vector_type(4)));
typedef f16  f16x8 __attribute__((ext_vector_type(8)));
typedef float f32x4 __attribute__((ext_vector_type(4)));

// ------------------------------ setup --------------------------------------

__global__ void k_count(const int* __restrict__ dst, int E, int* __restrict__ cnt, int N) {
    int e = blockIdx.x * blockDim.x + threadIdx.x;
    if (e >= E) return;
    int d = dst[e];
    if (d >= 0 && d < N) atomicAdd(&cnt[d], 1);
}

__global__ __launch_bounds__(256) void k_blocksum(const int* __restrict__ cnt, int N,
                                                  int* __restrict__ partial) {
    const int t  = threadIdx.x;
    const int b  = blockIdx.x;
    const int i0 = b * 1024 + t * 4;
    int s = 0;
#pragma unroll
    for (int j = 0; j < 4; ++j) {
        int i = i0 + j;
        if (i < N) s += cnt[i];
    }
#pragma unroll
    for (int o = 32; o > 0; o >>= 1) s += __shfl_xor(s, o);
    __shared__ int ws[4];
    if ((t & 63) == 0) ws[t >> 6] = s;
    __syncthreads();
    if (t == 0) partial[b] = ws[0] + ws[1] + ws[2] + ws[3];
}

__global__ __launch_bounds__(64) void k_scanpartials(int* __restrict__ partial, int numB,
                                                     int* __restrict__ base,
                                                     int* __restrict__ offs, int N) {
    const int t = threadIdx.x;
    int v = (t < numB) ? partial[t] : 0;
    int incl = v;
#pragma unroll
    for (int o = 1; o < 64; o <<= 1) {
        int u = __shfl_up(incl, o);
        if (t >= o) incl += u;
    }
    if (t < numB) base[t] = incl - v;
    if (t == 63) offs[N] = incl;
}

__global__ __launch_bounds__(256) void k_blockscan(const int* __restrict__ cnt, int N,
                                                   const int* __restrict__ base,
                                                   int* __restrict__ offs,
                                                   float* __restrict__ dinv,
                                                   int* __restrict__ cursor) {
    const int t  = threadIdx.x;
    const int b  = blockIdx.x;
    const int i0 = b * 1024 + t * 4;
    int c[4];
    int tsum = 0;
#pragma unroll
    for (int j = 0; j < 4; ++j) {
        int i = i0 + j;
        c[j] = (i < N) ? cnt[i] : 0;
        tsum += c[j];
    }
    int incl = tsum;
#pragma unroll
    for (int o = 1; o < 64; o <<= 1) {
        int u = __shfl_up(incl, o);
        if ((t & 63) >= o) incl += u;
    }
    __shared__ int ws[4];
    const int wid = t >> 6;
    if ((t & 63) == 63) ws[wid] = incl;
    __syncthreads();
    int wbase = 0;
    for (int w = 0; w < wid; ++w) wbase += ws[w];
    int run = base[b] + wbase + (incl - tsum);
#pragma unroll
    for (int j = 0; j < 4; ++j) {
        int i = i0 + j;
        if (i < N) {
            offs[i]   = run;
            run      += c[j];
            dinv[i]   = rsqrtf((float)(c[j] + 1));   // +1 self-loop
            cursor[i] = 0;
        }
    }
}

__global__ void k_scatter(const int* __restrict__ src, const int* __restrict__ dst, int E,
                          const int* __restrict__ offsets, int* __restrict__ cursor,
                          int* __restrict__ src_s, int N) {
    int e = blockIdx.x * blockDim.x + threadIdx.x;
    if (e >= E) return;
    int d = dst[e], s = src[e];
    if (d < 0 || d >= N || s < 0 || s >= N) return;
    int p = offsets[d] + atomicAdd(&cursor[d], 1);
    src_s[p] = s;
}

// --------------------------- fp16 conversions ------------------------------

__global__ void k_cvt_x(const float* __restrict__ X, f16* __restrict__ X16, int total4) {
    int i = blockIdx.x * blockDim.x + threadIdx.x;
    if (i >= total4) return;
    float4 v = *(const float4*)&X[(size_t)i * 4];
    f16x4 o = { (f16)v.x, (f16)v.y, (f16)v.z, (f16)v.w };
    *(f16x4*)&X16[(size_t)i * 4] = o;
}

// Wt16[n][k] = (f16) W[k][n]   (n in [0,OUT), k in [0,128))
template <int OUT>
__global__ void k_cvt_wt(const float* __restrict__ W, f16* __restrict__ Wt) {
    int i = blockIdx.x * 256 + threadIdx.x;
    if (i >= OUT * 128) return;
    int n = i >> 7, k = i & 127;
    Wt[i] = (f16)W[k * OUT + n];
}

// ------------------------------ MFMA GEMM ----------------------------------
// M16[m][n] = ( A16[m][:] @ W[:][n] ) * dinv[m],  K=128 fixed.
template <int OUT>
__global__ __launch_bounds__(256) void k_gemm_mfma(const f16* __restrict__ A,
                                                   const f16* __restrict__ Wt,
                                                   const float* __restrict__ dinv,
                                                   f16* __restrict__ M,
                                                   int N) {
    constexpr int K  = 128;
    constexpr int CW = OUT / 64;          // col-tiles per wave (2 or 1)
    __shared__ char smem[OUT * K * 2];    // W (swizzled), then reused as out-tile
    __shared__ float dl[64];

    const int t    = threadIdx.x;
    const int w    = t >> 6;
    const int lane = t & 63;
    const int ln   = lane & 15;
    const int lh   = lane >> 4;
    const int row0 = blockIdx.x * 64;

    {
        constexpr int NCH = OUT * 16;     // 16 x 16B chunks per 256B row
        for (int j = t; j < NCH; j += 256) {
            int n = j >> 4;
            uint32_t byte = (uint32_t)j * 16;
            uint32_t swz  = byte ^ (uint32_t)((n & 7) << 4);
            *(f16x8*)(smem + swz) = *(const f16x8*)&Wt[(size_t)j * 8];
        }
        if (t < 64) {
            int r = row0 + t;
            dl[t] = dinv[r < N ? r : (N - 1)];
        }
    }
    __syncthreads();

    f16x8 bfr[CW][4];
    const int c0 = w * CW;
#pragma unroll
    for (int c = 0; c < CW; ++c) {
        int n = (c0 + c) * 16 + ln;
#pragma unroll
        for (int q = 0; q < 4; ++q) {
            uint32_t byte = (uint32_t)(n * 256 + q * 64 + lh * 16);
            uint32_t swz  = byte ^ (uint32_t)((n & 7) << 4);
            bfr[c][q] = *(const f16x8*)(smem + swz);
        }
    }
    __syncthreads();

    f32x4 acc[4][CW];
#pragma unroll
    for (int s = 0; s < 4; ++s)
#pragma unroll
        for (int c = 0; c < CW; ++c)
            acc[s][c] = f32x4{0.f, 0.f, 0.f, 0.f};

#pragma unroll
    for (int s = 0; s < 4; ++s) {
        int m = row0 + s * 16 + ln;
        const f16* arow = A + (size_t)(m < N ? m : (N - 1)) * K;
#pragma unroll
        for (int q = 0; q < 4; ++q) {
            f16x8 a = *(const f16x8*)&arow[q * 32 + lh * 8];
#pragma unroll
            for (int c = 0; c < CW; ++c)
                acc[s][c] = __builtin_amdgcn_mfma_f32_16x16x32_f16(a, bfr[c][q], acc[s][c], 0, 0, 0);
        }
    }

    f16* ot = (f16*)smem;
#pragma unroll
    for (int s = 0; s < 4; ++s) {
#pragma unroll
        for (int c = 0; c < CW; ++c) {
            int col = (c0 + c) * 16 + ln;
#pragma unroll
            for (int r = 0; r < 4; ++r) {
                int rl = s * 16 + lh * 4 + r;
                ot[rl * OUT + col] = (f16)(acc[s][c][r] * dl[rl]);
            }
        }
    }
    __syncthreads();

    constexpr int CPR = OUT / 8;          // 16B chunks per row
    for (int j = t; j < 64 * CPR; j += 256) {
        int rl = j / CPR;
        if (row0 + rl < N)
            *(f16x8*)&M[(size_t)(row0 + rl) * OUT + (j % CPR) * 8] =
                *(const f16x8*)&ot[(size_t)j * 8];
    }
}

// ------------------------------ aggregation --------------------------------
// Wave per node; half-wave per edge (32 lanes x f16x4 = one 256B row);
// x4 unroll -> 8 edges / 4 vmem in flight. Cross-half combine via shfl_xor(32).
__global__ __launch_bounds__(256) void k_agg128_f16(const f16* __restrict__ M16,
                                                    const int* __restrict__ offs,
                                                    const int* __restrict__ srcs,
                                                    const float* __restrict__ dinv,
                                                    const float* __restrict__ bias,
                                                    f16* __restrict__ H16, int N) {
    const int lane = threadIdx.x & (WAVE - 1);
    const int half = lane >> 5;           // 0 or 1
    const int fl   = lane & 31;           // feature lane: feats 4*fl .. 4*fl+3
    const int node = blockIdx.x * 4 + (threadIdx.x >> 6);
    if (node >= N) return;

    const int fo = fl * 4;
    float a0 = 0.f, a1 = 0.f, a2 = 0.f, a3 = 0.f;
    if (half == 0) {   // self-loop term
        f16x4 v = *(const f16x4*)&M16[(size_t)node * 128 + fo];
        a0 = (float)v.x; a1 = (float)v.y; a2 = (float)v.z; a3 = (float)v.w;
    }

    const int e0 = offs[node], e1 = offs[node + 1];
    int e = e0;
    for (; e + 8 <= e1; e += 8) {
        int s0 = srcs[e + 0 + half];
        int s1 = srcs[e + 2 + half];
        int s2 = srcs[e + 4 + half];
        int s3 = srcs[e + 6 + half];
        f16x4 v0 = *(const f16x4*)&M16[(size_t)s0 * 128 + fo];
        f16x4 v1 = *(const f16x4*)&M16[(size_t)s1 * 128 + fo];
        f16x4 v2 = *(const f16x4*)&M16[(size_t)s2 * 128 + fo];
        f16x4 v3 = *(const f16x4*)&M16[(size_t)s3 * 128 + fo];
        a0 += (float)v0.x + (float)v1.x + (float)v2.x + (float)v3.x;
        a1 += (float)v0.y + (float)v1.y + (float)v2.y + (float)v3.y;
        a2 += (float)v0.z + (float)v1.z + (float)v2.z + (float)v3.z;
        a3 += (float)v0.w + (float)v1.w + (float)v2.w + (float)v3.w;
    }
    for (; e + 2 <= e1; e += 2) {
        int s = srcs[e + half];
        f16x4 v = *(const f16x4*)&M16[(size_t)s * 128 + fo];
        a0 += (float)v.x; a1 += (float)v.y; a2 += (float)v.z; a3 += (float)v.w;
    }
    if (e < e1 && half == 0) {
        f16x4 v = *(const f16x4*)&M16[(size_t)srcs[e] * 128 + fo];
        a0 += (float)v.x; a1 += (float)v.y; a2 += (float)v.z; a3 += (float)v.w;
    }

    a0 += __shfl_xor(a0, 32);
    a1 += __shfl_xor(a1, 32);
    a2 += __shfl_xor(a2, 32);
    a3 += __shfl_xor(a3, 32);

    if (half == 0) {
        const float dn = dinv[node];
        float4 b = *(const float4*)&bias[fo];
        f16x4 o = { (f16)fmaxf(a0 * dn + b.x, 0.f),
                    (f16)fmaxf(a1 * dn + b.y, 0.f),
                    (f16)fmaxf(a2 * dn + b.z, 0.f),
                    (f16)fmaxf(a3 * dn + b.w, 0.f) };
        *(f16x4*)&H16[(size_t)node * 128 + fo] = o;
    }
}

// Final layer: 64 feats (128B row = 32 lanes x f16x2); fused log_softmax.
__global__ __launch_bounds__(256) void k_agg64_lsm(const f16* __restrict__ M16,
                                                   const int* __restrict__ offs,
                                                   const int* __restrict__ srcs,
                                                   const float* __restrict__ dinv,
                                                   const float* __restrict__ bias,
                                                   float* __restrict__ Y, int N) {
    const int lane = threadIdx.x & (WAVE - 1);
    const int half = lane >> 5;
    const int fl   = lane & 31;           // classes 2*fl, 2*fl+1
    const int node = blockIdx.x * 4 + (threadIdx.x >> 6);
    if (node >= N) return;

    const int fo = fl * 2;
    float a0 = 0.f, a1 = 0.f;
    if (half == 0) {
        f16x2 v = *(const f16x2*)&M16[(size_t)node * 64 + fo];
        a0 = (float)v.x; a1 = (float)v.y;
    }

    const int e0 = offs[node], e1 = offs[node + 1];
    int e = e0;
    for (; e + 8 <= e1; e += 8) {
        int s0 = srcs[e + 0 + half];
        int s1 = srcs[e + 2 + half];
        int s2 = srcs[e + 4 + half];
        int s3 = srcs[e + 6 + half];
        f16x2 v0 = *(const f16x2*)&M16[(size_t)s0 * 64 + fo];
        f16x2 v1 = *(const f16x2*)&M16[(size_t)s1 * 64 + fo];
        f16x2 v2 = *(const f16x2*)&M16[(size_t)s2 * 64 + fo];
        f16x2 v3 = *(const f16x2*)&M16[(size_t)s3 * 64 + fo];
        a0 += (float)v0.x + (float)v1.x + (float)v2.x + (float)v3.x;
        a1 += (float)v0.y + (float)v1.y + (float)v2.y + (float)v3.y;
    }
    for (; e + 2 <= e1; e += 2) {
        int s = srcs[e + half];
        f16x2 v = *(const f16x2*)&M16[(size_t)s * 64 + fo];
        a0 += (float)v.x; a1 += (float)v.y;
    }
    if (e < e1 && half == 0) {
        f16x2 v = *(const f16x2*)&M16[(size_t)srcs[e] * 64 + fo];
        a0 += (float)v.x; a1 += (float)v.y;
    }

    a0 += __shfl_xor(a0, 32);
    a1 += __shfl_xor(a1, 32);

    // lanes 0..31 now hold the full logit pair; softmax over 64 classes
    const float dn = dinv[node];
    float v0 = a0 * dn + bias[fo];
    float v1 = a1 * dn + bias[fo + 1];
    float m = fmaxf(v0, v1);
#pragma unroll
    for (int o = 16; o > 0; o >>= 1) m = fmaxf(m, __shfl_xor(m, o));
    float s = expf(v0 - m) + expf(v1 - m);
#pragma unroll
    for (int o = 16; o > 0; o >>= 1) s += __shfl_xor(s, o);
    if (half == 0) {
        float ls = logf(s);
        float2 o2 = make_float2(v0 - m - ls, v1 - m - ls);
        *(float2*)&Y[(size_t)node * 64 + fo] = o2;
    }
}

// ---------------------------------------------------------------------------

extern "C" void kernel_launch(void* const* d_in, const int* in_sizes, int n_in,
                              void* d_out, int out_size, void* d_ws, size_t ws_size,
                              hipStream_t stream) {
    const float* x  = (const float*)d_in[0];
    const int*   ei = (const int*)d_in[1];
    const float* W1 = (const float*)d_in[2];
    const float* b1 = (const float*)d_in[3];
    const float* W2 = (const float*)d_in[4];
    const float* b2 = (const float*)d_in[5];
    const float* Wf = (const float*)d_in[6];
    const float* bf = (const float*)d_in[7];
    float* out = (float*)d_out;

    const int N = in_sizes[0] / 128;
    const int E = in_sizes[1] / 2;
    const int* src = ei;
    const int* dst = ei + E;

    char* ws = (char*)d_ws;
    auto alloc = [&](size_t bytes) -> void* {
        void* p = ws;
        ws += (bytes + 255) & ~(size_t)255;
        return p;
    };
    const int numB = (N + 1023) / 1024;
    int*   cnt    = (int*)alloc((size_t)N * 4);
    int*   cursor = (int*)alloc((size_t)N * 4);
    int*   offs   = (int*)alloc((size_t)(N + 1) * 4);
    float* dinv   = (float*)alloc((size_t)N * 4);
    int*   part   = (int*)alloc((size_t)numB * 4);
    int*   pbase  = (int*)alloc((size_t)numB * 4);
    int*   src_s  = (int*)alloc((size_t)E * 4);
    f16*   x16    = (f16*)alloc((size_t)N * 128 * 2);
    f16*   m16    = (f16*)alloc((size_t)N * 128 * 2);
    f16*   h16    = (f16*)alloc((size_t)N * 128 * 2);
    f16*   Wt1    = (f16*)alloc(128 * 128 * 2);
    f16*   Wt2    = (f16*)alloc(128 * 128 * 2);
    f16*   Wtf    = (f16*)alloc(128 * 64 * 2);

    hipMemsetAsync(cnt, 0, (size_t)N * 4, stream);

    const int TB = 256;
    k_count<<<(E + TB - 1) / TB, TB, 0, stream>>>(dst, E, cnt, N);
    k_blocksum<<<numB, 256, 0, stream>>>(cnt, N, part);
    k_scanpartials<<<1, 64, 0, stream>>>(part, numB, pbase, offs, N);
    k_blockscan<<<numB, 256, 0, stream>>>(cnt, N, pbase, offs, dinv, cursor);
    k_scatter<<<(E + TB - 1) / TB, TB, 0, stream>>>(src, dst, E, offs, cursor, src_s, N);

    const int total4 = N * 32;
    k_cvt_x<<<(total4 + TB - 1) / TB, TB, 0, stream>>>(x, x16, total4);
    k_cvt_wt<128><<<64, 256, 0, stream>>>(W1, Wt1);
    k_cvt_wt<128><<<64, 256, 0, stream>>>(W2, Wt2);
    k_cvt_wt<64><<<32, 256, 0, stream>>>(Wf, Wtf);

    const int gemm_grid = (N + 63) / 64;
    const int agg_grid  = (N + 3) / 4;

    k_gemm_mfma<128><<<gemm_grid, 256, 0, stream>>>(x16, Wt1, dinv, m16, N);
    k_agg128_f16<<<agg_grid, 256, 0, stream>>>(m16, offs, src_s, dinv, b1, h16, N);

    k_gemm_mfma<128><<<gemm_grid, 256, 0, stream>>>(h16, Wt2, dinv, m16, N);
    k_agg128_f16<<<agg_grid, 256, 0, stream>>>(m16, offs, src_s, dinv, b2, h16, N);

    k_gemm_mfma<64><<<gemm_grid, 256, 0, stream>>>(h16, Wtf, dinv, m16, N);
    k_agg64_lsm<<<agg_grid, 256, 0, stream>>>(m16, offs, src_s, dinv, bf, out, N);
}

// Round 5
// 207.044 us; speedup vs baseline: 2.2307x; 1.0887x over previous
//
#include <hip/hip_runtime.h>
#include <cstdint>
#include <cstddef>

// ---------------------------------------------------------------------------
// 3-layer GCN, fp16 message pipeline:
//   m' = (h @ W) * dinv[row]      (MFMA f16 GEMM, fp32 accum, fp16 out)
//   h' = relu(dinv[n] * (m'[n] + sum_{e->n} m'[src]) + b)   (fp16 out)
// final layer: logits fp32 + log_softmax.
// CSR-by-dst built per call (count -> hierarchical scan -> scatter).
// Aggregation: quarter-wave (16 lanes x f16x8) per edge row, 16 edges per
// masked round -> deg<=16 nodes take ONE L3-latency round-trip.
// ---------------------------------------------------------------------------

#define WAVE 64
typedef _Float16 f16;
typedef f16  f16x2 __attribute__((ext_vector_type(2)));
typedef f16  f16x4 __attribute__((ext_vector_type(4)));
typedef f16  f16x8 __attribute__((ext_vector_type(8)));
typedef float f32x4 __attribute__((ext_vector_type(4)));

// ------------------------------ setup --------------------------------------

__global__ void k_count(const int* __restrict__ dst, int E, int* __restrict__ cnt, int N) {
    int e = blockIdx.x * blockDim.x + threadIdx.x;
    if (e >= E) return;
    int d = dst[e];
    if (d >= 0 && d < N) atomicAdd(&cnt[d], 1);
}

__global__ __launch_bounds__(256) void k_blocksum(const int* __restrict__ cnt, int N,
                                                  int* __restrict__ partial) {
    const int t  = threadIdx.x;
    const int b  = blockIdx.x;
    const int i0 = b * 1024 + t * 4;
    int s = 0;
#pragma unroll
    for (int j = 0; j < 4; ++j) {
        int i = i0 + j;
        if (i < N) s += cnt[i];
    }
#pragma unroll
    for (int o = 32; o > 0; o >>= 1) s += __shfl_xor(s, o);
    __shared__ int ws[4];
    if ((t & 63) == 0) ws[t >> 6] = s;
    __syncthreads();
    if (t == 0) partial[b] = ws[0] + ws[1] + ws[2] + ws[3];
}

__global__ __launch_bounds__(64) void k_scanpartials(int* __restrict__ partial, int numB,
                                                     int* __restrict__ base,
                                                     int* __restrict__ offs, int N) {
    const int t = threadIdx.x;
    int v = (t < numB) ? partial[t] : 0;
    int incl = v;
#pragma unroll
    for (int o = 1; o < 64; o <<= 1) {
        int u = __shfl_up(incl, o);
        if (t >= o) incl += u;
    }
    if (t < numB) base[t] = incl - v;
    if (t == 63) offs[N] = incl;
}

__global__ __launch_bounds__(256) void k_blockscan(const int* __restrict__ cnt, int N,
                                                   const int* __restrict__ base,
                                                   int* __restrict__ offs,
                                                   float* __restrict__ dinv,
                                                   int* __restrict__ cursor) {
    const int t  = threadIdx.x;
    const int b  = blockIdx.x;
    const int i0 = b * 1024 + t * 4;
    int c[4];
    int tsum = 0;
#pragma unroll
    for (int j = 0; j < 4; ++j) {
        int i = i0 + j;
        c[j] = (i < N) ? cnt[i] : 0;
        tsum += c[j];
    }
    int incl = tsum;
#pragma unroll
    for (int o = 1; o < 64; o <<= 1) {
        int u = __shfl_up(incl, o);
        if ((t & 63) >= o) incl += u;
    }
    __shared__ int ws[4];
    const int wid = t >> 6;
    if ((t & 63) == 63) ws[wid] = incl;
    __syncthreads();
    int wbase = 0;
    for (int w = 0; w < wid; ++w) wbase += ws[w];
    int run = base[b] + wbase + (incl - tsum);
#pragma unroll
    for (int j = 0; j < 4; ++j) {
        int i = i0 + j;
        if (i < N) {
            offs[i]   = run;
            run      += c[j];
            dinv[i]   = rsqrtf((float)(c[j] + 1));   // +1 self-loop
            cursor[i] = 0;
        }
    }
}

__global__ void k_scatter(const int* __restrict__ src, const int* __restrict__ dst, int E,
                          const int* __restrict__ offsets, int* __restrict__ cursor,
                          int* __restrict__ src_s, int N) {
    int e = blockIdx.x * blockDim.x + threadIdx.x;
    if (e >= E) return;
    int d = dst[e], s = src[e];
    if (d < 0 || d >= N || s < 0 || s >= N) return;
    int p = offsets[d] + atomicAdd(&cursor[d], 1);
    src_s[p] = s;
}

// --------------------------- fp16 conversions ------------------------------

__global__ void k_cvt_x(const float* __restrict__ X, f16* __restrict__ X16, int total4) {
    int i = blockIdx.x * blockDim.x + threadIdx.x;
    if (i >= total4) return;
    float4 v = *(const float4*)&X[(size_t)i * 4];
    f16x4 o = { (f16)v.x, (f16)v.y, (f16)v.z, (f16)v.w };
    *(f16x4*)&X16[(size_t)i * 4] = o;
}

// All three weight transposes in one launch.
// Wt[n][k] = (f16) W[k][n]; W1/W2: 128x128, Wf: 128x64.
__global__ void k_cvt_w_all(const float* __restrict__ W1, const float* __restrict__ W2,
                            const float* __restrict__ Wf,
                            f16* __restrict__ Wt1, f16* __restrict__ Wt2,
                            f16* __restrict__ Wtf) {
    int i = blockIdx.x * 256 + threadIdx.x;
    if (i < 16384) {
        int n = i >> 7, k = i & 127;
        Wt1[i] = (f16)W1[k * 128 + n];
    } else if (i < 32768) {
        int j = i - 16384;
        int n = j >> 7, k = j & 127;
        Wt2[j] = (f16)W2[k * 128 + n];
    } else if (i < 40960) {
        int j = i - 32768;
        int n = j >> 7, k = j & 127;
        Wtf[j] = (f16)Wf[k * 64 + n];
    }
}

// ------------------------------ MFMA GEMM ----------------------------------
// M16[m][n] = ( A16[m][:] @ W[:][n] ) * dinv[m],  K=128 fixed.
template <int OUT>
__global__ __launch_bounds__(256) void k_gemm_mfma(const f16* __restrict__ A,
                                                   const f16* __restrict__ Wt,
                                                   const float* __restrict__ dinv,
                                                   f16* __restrict__ M,
                                                   int N) {
    constexpr int K  = 128;
    constexpr int CW = OUT / 64;          // col-tiles per wave (2 or 1)
    __shared__ char smem[OUT * K * 2];    // W (swizzled), then reused as out-tile
    __shared__ float dl[64];

    const int t    = threadIdx.x;
    const int w    = t >> 6;
    const int lane = t & 63;
    const int ln   = lane & 15;
    const int lh   = lane >> 4;
    const int row0 = blockIdx.x * 64;

    {
        constexpr int NCH = OUT * 16;     // 16 x 16B chunks per 256B row
        for (int j = t; j < NCH; j += 256) {
            int n = j >> 4;
            uint32_t byte = (uint32_t)j * 16;
            uint32_t swz  = byte ^ (uint32_t)((n & 7) << 4);
            *(f16x8*)(smem + swz) = *(const f16x8*)&Wt[(size_t)j * 8];
        }
        if (t < 64) {
            int r = row0 + t;
            dl[t] = dinv[r < N ? r : (N - 1)];
        }
    }
    __syncthreads();

    f16x8 bfr[CW][4];
    const int c0 = w * CW;
#pragma unroll
    for (int c = 0; c < CW; ++c) {
        int n = (c0 + c) * 16 + ln;
#pragma unroll
        for (int q = 0; q < 4; ++q) {
            uint32_t byte = (uint32_t)(n * 256 + q * 64 + lh * 16);
            uint32_t swz  = byte ^ (uint32_t)((n & 7) << 4);
            bfr[c][q] = *(const f16x8*)(smem + swz);
        }
    }
    __syncthreads();

    f32x4 acc[4][CW];
#pragma unroll
    for (int s = 0; s < 4; ++s)
#pragma unroll
        for (int c = 0; c < CW; ++c)
            acc[s][c] = f32x4{0.f, 0.f, 0.f, 0.f};

#pragma unroll
    for (int s = 0; s < 4; ++s) {
        int m = row0 + s * 16 + ln;
        const f16* arow = A + (size_t)(m < N ? m : (N - 1)) * K;
#pragma unroll
        for (int q = 0; q < 4; ++q) {
            f16x8 a = *(const f16x8*)&arow[q * 32 + lh * 8];
#pragma unroll
            for (int c = 0; c < CW; ++c)
                acc[s][c] = __builtin_amdgcn_mfma_f32_16x16x32_f16(a, bfr[c][q], acc[s][c], 0, 0, 0);
        }
    }

    f16* ot = (f16*)smem;
#pragma unroll
    for (int s = 0; s < 4; ++s) {
#pragma unroll
        for (int c = 0; c < CW; ++c) {
            int col = (c0 + c) * 16 + ln;
#pragma unroll
            for (int r = 0; r < 4; ++r) {
                int rl = s * 16 + lh * 4 + r;
                ot[rl * OUT + col] = (f16)(acc[s][c][r] * dl[rl]);
            }
        }
    }
    __syncthreads();

    constexpr int CPR = OUT / 8;          // 16B chunks per row
    for (int j = t; j < 64 * CPR; j += 256) {
        int rl = j / CPR;
        if (row0 + rl < N)
            *(f16x8*)&M[(size_t)(row0 + rl) * OUT + (j % CPR) * 8] =
                *(const f16x8*)&ot[(size_t)j * 8];
    }
}

// ------------------------------ aggregation --------------------------------
// Wave per node. Quarter-wave (16 lanes x f16x8 = 256B row) per edge;
// 4 edges/round x4 unroll = 16 edges per masked round, all loads in flight.
// deg<=16 -> single memory round. Cross-quarter combine: shfl_xor 16,32.
__global__ __launch_bounds__(256) void k_agg128_f16(const f16* __restrict__ M16,
                                                    const int* __restrict__ offs,
                                                    const int* __restrict__ srcs,
                                                    const float* __restrict__ dinv,
                                                    const float* __restrict__ bias,
                                                    f16* __restrict__ H16, int N) {
    const int lane = threadIdx.x & (WAVE - 1);
    const int q    = lane >> 4;           // quarter 0..3
    const int fl   = lane & 15;           // feature lane
    const int fo   = fl * 8;              // feats fo..fo+7
    const int node = blockIdx.x * 4 + (threadIdx.x >> 6);
    if (node >= N) return;

    float a[8] = {0.f, 0.f, 0.f, 0.f, 0.f, 0.f, 0.f, 0.f};
    if (q == 0) {   // self-loop term
        f16x8 v = *(const f16x8*)&M16[(size_t)node * 128 + fo];
#pragma unroll
        for (int i = 0; i < 8; ++i) a[i] = (float)v[i];
    }

    const int e0 = offs[node], e1 = offs[node + 1];
    for (int base = e0; base < e1; base += 16) {
        const int i0 = base + q, i1 = base + 4 + q, i2 = base + 8 + q, i3 = base + 12 + q;
        const int s0 = srcs[i0 < e1 ? i0 : e0];
        const int s1 = srcs[i1 < e1 ? i1 : e0];
        const int s2 = srcs[i2 < e1 ? i2 : e0];
        const int s3 = srcs[i3 < e1 ? i3 : e0];
        const float w0 = i0 < e1 ? 1.f : 0.f;
        const float w1 = i1 < e1 ? 1.f : 0.f;
        const float w2 = i2 < e1 ? 1.f : 0.f;
        const float w3 = i3 < e1 ? 1.f : 0.f;
        f16x8 v0 = *(const f16x8*)&M16[(size_t)s0 * 128 + fo];
        f16x8 v1 = *(const f16x8*)&M16[(size_t)s1 * 128 + fo];
        f16x8 v2 = *(const f16x8*)&M16[(size_t)s2 * 128 + fo];
        f16x8 v3 = *(const f16x8*)&M16[(size_t)s3 * 128 + fo];
#pragma unroll
        for (int i = 0; i < 8; ++i)
            a[i] += w0 * (float)v0[i] + w1 * (float)v1[i]
                  + w2 * (float)v2[i] + w3 * (float)v3[i];
    }

#pragma unroll
    for (int i = 0; i < 8; ++i) {
        a[i] += __shfl_xor(a[i], 16);
        a[i] += __shfl_xor(a[i], 32);
    }

    if (q == 0) {
        const float dn = dinv[node];
        float4 b0 = *(const float4*)&bias[fo];
        float4 b1 = *(const float4*)&bias[fo + 4];
        f16x8 o;
        o[0] = (f16)fmaxf(a[0] * dn + b0.x, 0.f);
        o[1] = (f16)fmaxf(a[1] * dn + b0.y, 0.f);
        o[2] = (f16)fmaxf(a[2] * dn + b0.z, 0.f);
        o[3] = (f16)fmaxf(a[3] * dn + b0.w, 0.f);
        o[4] = (f16)fmaxf(a[4] * dn + b1.x, 0.f);
        o[5] = (f16)fmaxf(a[5] * dn + b1.y, 0.f);
        o[6] = (f16)fmaxf(a[6] * dn + b1.z, 0.f);
        o[7] = (f16)fmaxf(a[7] * dn + b1.w, 0.f);
        *(f16x8*)&H16[(size_t)node * 128 + fo] = o;
    }
}

// Final layer: 64 feats; quarter-wave (16 lanes x f16x4 = 128B row) per edge;
// 16 edges per masked round; fused bias + log_softmax within quarter 0.
__global__ __launch_bounds__(256) void k_agg64_lsm(const f16* __restrict__ M16,
                                                   const int* __restrict__ offs,
                                                   const int* __restrict__ srcs,
                                                   const float* __restrict__ dinv,
                                                   const float* __restrict__ bias,
                                                   float* __restrict__ Y, int N) {
    const int lane = threadIdx.x & (WAVE - 1);
    const int q    = lane >> 4;
    const int fl   = lane & 15;           // classes 4*fl .. 4*fl+3
    const int fo   = fl * 4;
    const int node = blockIdx.x * 4 + (threadIdx.x >> 6);
    if (node >= N) return;

    float a[4] = {0.f, 0.f, 0.f, 0.f};
    if (q == 0) {
        f16x4 v = *(const f16x4*)&M16[(size_t)node * 64 + fo];
#pragma unroll
        for (int i = 0; i < 4; ++i) a[i] = (float)v[i];
    }

    const int e0 = offs[node], e1 = offs[node + 1];
    for (int base = e0; base < e1; base += 16) {
        const int i0 = base + q, i1 = base + 4 + q, i2 = base + 8 + q, i3 = base + 12 + q;
        const int s0 = srcs[i0 < e1 ? i0 : e0];
        const int s1 = srcs[i1 < e1 ? i1 : e0];
        const int s2 = srcs[i2 < e1 ? i2 : e0];
        const int s3 = srcs[i3 < e1 ? i3 : e0];
        const float w0 = i0 < e1 ? 1.f : 0.f;
        const float w1 = i1 < e1 ? 1.f : 0.f;
        const float w2 = i2 < e1 ? 1.f : 0.f;
        const float w3 = i3 < e1 ? 1.f : 0.f;
        f16x4 v0 = *(const f16x4*)&M16[(size_t)s0 * 64 + fo];
        f16x4 v1 = *(const f16x4*)&M16[(size_t)s1 * 64 + fo];
        f16x4 v2 = *(const f16x4*)&M16[(size_t)s2 * 64 + fo];
        f16x4 v3 = *(const f16x4*)&M16[(size_t)s3 * 64 + fo];
#pragma unroll
        for (int i = 0; i < 4; ++i)
            a[i] += w0 * (float)v0[i] + w1 * (float)v1[i]
                  + w2 * (float)v2[i] + w3 * (float)v3[i];
    }

#pragma unroll
    for (int i = 0; i < 4; ++i) {
        a[i] += __shfl_xor(a[i], 16);
        a[i] += __shfl_xor(a[i], 32);
    }

    // logits + log_softmax across 64 classes held as 16 lanes x 4 (quarter 0)
    const float dn = dinv[node];
    float4 b = *(const float4*)&bias[fo];
    float v0 = a[0] * dn + b.x;
    float v1 = a[1] * dn + b.y;
    float v2 = a[2] * dn + b.z;
    float v3 = a[3] * dn + b.w;
    float m = fmaxf(fmaxf(v0, v1), fmaxf(v2, v3));
#pragma unroll
    for (int o = 8; o > 0; o >>= 1) m = fmaxf(m, __shfl_xor(m, o));   // width-16
    float s = expf(v0 - m) + expf(v1 - m) + expf(v2 - m) + expf(v3 - m);
#pragma unroll
    for (int o = 8; o > 0; o >>= 1) s += __shfl_xor(s, o);
    if (q == 0) {
        float ls = logf(s);
        float4 o4 = make_float4(v0 - m - ls, v1 - m - ls, v2 - m - ls, v3 - m - ls);
        *(float4*)&Y[(size_t)node * 64 + fo] = o4;
    }
}

// ---------------------------------------------------------------------------

extern "C" void kernel_launch(void* const* d_in, const int* in_sizes, int n_in,
                              void* d_out, int out_size, void* d_ws, size_t ws_size,
                              hipStream_t stream) {
    const float* x  = (const float*)d_in[0];
    const int*   ei = (const int*)d_in[1];
    const float* W1 = (const float*)d_in[2];
    const float* b1 = (const float*)d_in[3];
    const float* W2 = (const float*)d_in[4];
    const float* b2 = (const float*)d_in[5];
    const float* Wf = (const float*)d_in[6];
    const float* bf = (const float*)d_in[7];
    float* out = (float*)d_out;

    const int N = in_sizes[0] / 128;
    const int E = in_sizes[1] / 2;
    const int* src = ei;
    const int* dst = ei + E;

    char* ws = (char*)d_ws;
    auto alloc = [&](size_t bytes) -> void* {
        void* p = ws;
        ws += (bytes + 255) & ~(size_t)255;
        return p;
    };
    const int numB = (N + 1023) / 1024;
    int*   cnt    = (int*)alloc((size_t)N * 4);
    int*   cursor = (int*)alloc((size_t)N * 4);
    int*   offs   = (int*)alloc((size_t)(N + 1) * 4);
    float* dinv   = (float*)alloc((size_t)N * 4);
    int*   part   = (int*)alloc((size_t)numB * 4);
    int*   pbase  = (int*)alloc((size_t)numB * 4);
    int*   src_s  = (int*)alloc((size_t)E * 4);
    f16*   x16    = (f16*)alloc((size_t)N * 128 * 2);
    f16*   m16    = (f16*)alloc((size_t)N * 128 * 2);
    f16*   h16    = (f16*)alloc((size_t)N * 128 * 2);
    f16*   Wt1    = (f16*)alloc(128 * 128 * 2);
    f16*   Wt2    = (f16*)alloc(128 * 128 * 2);
    f16*   Wtf    = (f16*)alloc(128 * 64 * 2);

    hipMemsetAsync(cnt, 0, (size_t)N * 4, stream);

    const int TB = 256;
    k_count<<<(E + TB - 1) / TB, TB, 0, stream>>>(dst, E, cnt, N);
    k_blocksum<<<numB, 256, 0, stream>>>(cnt, N, part);
    k_scanpartials<<<1, 64, 0, stream>>>(part, numB, pbase, offs, N);
    k_blockscan<<<numB, 256, 0, stream>>>(cnt, N, pbase, offs, dinv, cursor);
    k_scatter<<<(E + TB - 1) / TB, TB, 0, stream>>>(src, dst, E, offs, cursor, src_s, N);

    const int total4 = N * 32;
    k_cvt_x<<<(total4 + TB - 1) / TB, TB, 0, stream>>>(x, x16, total4);
    k_cvt_w_all<<<160, 256, 0, stream>>>(W1, W2, Wf, Wt1, Wt2, Wtf);

    const int gemm_grid = (N + 63) / 64;
    const int agg_grid  = (N + 3) / 4;

    k_gemm_mfma<128><<<gemm_grid, 256, 0, stream>>>(x16, Wt1, dinv, m16, N);
    k_agg128_f16<<<agg_grid, 256, 0, stream>>>(m16, offs, src_s, dinv, b1, h16, N);

    k_gemm_mfma<128><<<gemm_grid, 256, 0, stream>>>(h16, Wt2, dinv, m16, N);
    k_agg128_f16<<<agg_grid, 256, 0, stream>>>(m16, offs, src_s, dinv, b2, h16, N);

    k_gemm_mfma<64><<<gemm_grid, 256, 0, stream>>>(h16, Wtf, dinv, m16, N);
    k_agg64_lsm<<<agg_grid, 256, 0, stream>>>(m16, offs, src_s, dinv, bf, out, N);
}

// Round 6
// 201.503 us; speedup vs baseline: 2.2920x; 1.0275x over previous
//
#include <hip/hip_runtime.h>
#include <cstdint>
#include <cstddef>

// ---------------------------------------------------------------------------
// 3-layer GCN, fp16 message pipeline:
//   m' = (h @ W) * dinv[row]      (MFMA f16 GEMM, fp32 accum, fp16 out)
//   h' = relu(dinv[n] * (m'[n] + sum_{e->n} m'[src]) + b)   (fp16 out)
// final layer: logits fp32 + log_softmax.
// CSR-by-dst built per call (count -> scan (block-level, partials reduced
// in-kernel) -> scatter). Aggregation: HALF-WAVE per node; 16 lanes x f16x8
// per edge row, 16 edges per masked round, 8 row-loads in flight per wave,
// 2 nodes retired per wave-latency (latency-bound regime).
// GEMM layer 1 reads fp32 X directly (cvt fused into fragment load).
// ---------------------------------------------------------------------------

#define WAVE 64
typedef _Float16 f16;
typedef f16  f16x2 __attribute__((ext_vector_type(2)));
typedef f16  f16x4 __attribute__((ext_vector_type(4)));
typedef f16  f16x8 __attribute__((ext_vector_type(8)));
typedef float f32x4 __attribute__((ext_vector_type(4)));

// ------------------------------ setup --------------------------------------

__global__ void k_count(const int* __restrict__ dst, int E, int* __restrict__ cnt, int N) {
    int e = blockIdx.x * blockDim.x + threadIdx.x;
    if (e >= E) return;
    int d = dst[e];
    if (d >= 0 && d < N) atomicAdd(&cnt[d], 1);
}

__global__ __launch_bounds__(256) void k_blocksum(const int* __restrict__ cnt, int N,
                                                  int* __restrict__ partial) {
    const int t  = threadIdx.x;
    const int b  = blockIdx.x;
    const int i0 = b * 1024 + t * 4;
    int s = 0;
#pragma unroll
    for (int j = 0; j < 4; ++j) {
        int i = i0 + j;
        if (i < N) s += cnt[i];
    }
#pragma unroll
    for (int o = 32; o > 0; o >>= 1) s += __shfl_xor(s, o);
    __shared__ int ws[4];
    if ((t & 63) == 0) ws[t >> 6] = s;
    __syncthreads();
    if (t == 0) partial[b] = ws[0] + ws[1] + ws[2] + ws[3];
}

// local scan + base (base = sum of partials[0..b), reduced in-kernel by wave 0);
// also emits dinv and zeroes cursor; last block writes offs[N].
__global__ __launch_bounds__(256) void k_blockscan(const int* __restrict__ cnt, int N,
                                                   const int* __restrict__ partial, int numB,
                                                   int* __restrict__ offs,
                                                   float* __restrict__ dinv,
                                                   int* __restrict__ cursor) {
    const int t  = threadIdx.x;
    const int b  = blockIdx.x;
    const int i0 = b * 1024 + t * 4;
    __shared__ int sbase;
    __shared__ int ws[4];

    if (t < 64) {           // wave 0: base = sum partial[0..b)
        int v = 0;
        for (int i = t; i < b; i += 64) v += partial[i];
#pragma unroll
        for (int o = 32; o > 0; o >>= 1) v += __shfl_xor(v, o);
        if (t == 0) sbase = v;
    }

    int c[4];
    int tsum = 0;
#pragma unroll
    for (int j = 0; j < 4; ++j) {
        int i = i0 + j;
        c[j] = (i < N) ? cnt[i] : 0;
        tsum += c[j];
    }
    int incl = tsum;
#pragma unroll
    for (int o = 1; o < 64; o <<= 1) {
        int u = __shfl_up(incl, o);
        if ((t & 63) >= o) incl += u;
    }
    const int wid = t >> 6;
    if ((t & 63) == 63) ws[wid] = incl;
    __syncthreads();
    int wbase = 0;
    for (int w = 0; w < wid; ++w) wbase += ws[w];
    int run = sbase + wbase + (incl - tsum);
#pragma unroll
    for (int j = 0; j < 4; ++j) {
        int i = i0 + j;
        if (i < N) {
            offs[i]   = run;
            run      += c[j];
            dinv[i]   = rsqrtf((float)(c[j] + 1));   // +1 self-loop
            cursor[i] = 0;
        }
    }
    if (b == numB - 1 && t == 0)
        offs[N] = sbase + ws[0] + ws[1] + ws[2] + ws[3];
}

__global__ void k_scatter(const int* __restrict__ src, const int* __restrict__ dst, int E,
                          const int* __restrict__ offsets, int* __restrict__ cursor,
                          int* __restrict__ src_s, int N) {
    int e = blockIdx.x * blockDim.x + threadIdx.x;
    if (e >= E) return;
    int d = dst[e], s = src[e];
    if (d < 0 || d >= N || s < 0 || s >= N) return;
    int p = offsets[d] + atomicAdd(&cursor[d], 1);
    src_s[p] = s;
}

// All three weight transposes in one launch.
// Wt[n][k] = (f16) W[k][n]; W1/W2: 128x128, Wf: 128x64.
__global__ void k_cvt_w_all(const float* __restrict__ W1, const float* __restrict__ W2,
                            const float* __restrict__ Wf,
                            f16* __restrict__ Wt1, f16* __restrict__ Wt2,
                            f16* __restrict__ Wtf) {
    int i = blockIdx.x * 256 + threadIdx.x;
    if (i < 16384) {
        int n = i >> 7, k = i & 127;
        Wt1[i] = (f16)W1[k * 128 + n];
    } else if (i < 32768) {
        int j = i - 16384;
        int n = j >> 7, k = j & 127;
        Wt2[j] = (f16)W2[k * 128 + n];
    } else if (i < 40960) {
        int j = i - 32768;
        int n = j >> 7, k = j & 127;
        Wtf[j] = (f16)Wf[k * 64 + n];
    }
}

// ------------------------------ MFMA GEMM ----------------------------------
// M16[m][n] = ( A[m][:] @ W[:][n] ) * dinv[m],  K=128 fixed.
// AF32: A is fp32 (layer 1, conversion fused into fragment load).
template <int OUT, bool AF32>
__global__ __launch_bounds__(256) void k_gemm_mfma(const void* __restrict__ Av,
                                                   const f16* __restrict__ Wt,
                                                   const float* __restrict__ dinv,
                                                   f16* __restrict__ M,
                                                   int N) {
    constexpr int K  = 128;
    constexpr int CW = OUT / 64;          // col-tiles per wave (2 or 1)
    __shared__ char smem[OUT * K * 2];    // W (swizzled), then reused as out-tile
    __shared__ float dl[64];

    const int t    = threadIdx.x;
    const int w    = t >> 6;
    const int lane = t & 63;
    const int ln   = lane & 15;
    const int lh   = lane >> 4;
    const int row0 = blockIdx.x * 64;

    {
        constexpr int NCH = OUT * 16;     // 16 x 16B chunks per 256B row
        for (int j = t; j < NCH; j += 256) {
            int n = j >> 4;
            uint32_t byte = (uint32_t)j * 16;
            uint32_t swz  = byte ^ (uint32_t)((n & 7) << 4);
            *(f16x8*)(smem + swz) = *(const f16x8*)&Wt[(size_t)j * 8];
        }
        if (t < 64) {
            int r = row0 + t;
            dl[t] = dinv[r < N ? r : (N - 1)];
        }
    }
    __syncthreads();

    f16x8 bfr[CW][4];
    const int c0 = w * CW;
#pragma unroll
    for (int c = 0; c < CW; ++c) {
        int n = (c0 + c) * 16 + ln;
#pragma unroll
        for (int q = 0; q < 4; ++q) {
            uint32_t byte = (uint32_t)(n * 256 + q * 64 + lh * 16);
            uint32_t swz  = byte ^ (uint32_t)((n & 7) << 4);
            bfr[c][q] = *(const f16x8*)(smem + swz);
        }
    }
    __syncthreads();

    f32x4 acc[4][CW];
#pragma unroll
    for (int s = 0; s < 4; ++s)
#pragma unroll
        for (int c = 0; c < CW; ++c)
            acc[s][c] = f32x4{0.f, 0.f, 0.f, 0.f};

#pragma unroll
    for (int s = 0; s < 4; ++s) {
        int m = row0 + s * 16 + ln;
        const size_t mrow = (size_t)(m < N ? m : (N - 1)) * K;
#pragma unroll
        for (int q = 0; q < 4; ++q) {
            f16x8 a;
            if constexpr (AF32) {
                const float* ap = (const float*)Av + mrow + q * 32 + lh * 8;
                float4 x0 = *(const float4*)ap;
                float4 x1 = *(const float4*)(ap + 4);
                a = f16x8{ (f16)x0.x, (f16)x0.y, (f16)x0.z, (f16)x0.w,
                           (f16)x1.x, (f16)x1.y, (f16)x1.z, (f16)x1.w };
            } else {
                a = *(const f16x8*)((const f16*)Av + mrow + q * 32 + lh * 8);
            }
#pragma unroll
            for (int c = 0; c < CW; ++c)
                acc[s][c] = __builtin_amdgcn_mfma_f32_16x16x32_f16(a, bfr[c][q], acc[s][c], 0, 0, 0);
        }
    }

    f16* ot = (f16*)smem;
#pragma unroll
    for (int s = 0; s < 4; ++s) {
#pragma unroll
        for (int c = 0; c < CW; ++c) {
            int col = (c0 + c) * 16 + ln;
#pragma unroll
            for (int r = 0; r < 4; ++r) {
                int rl = s * 16 + lh * 4 + r;
                ot[rl * OUT + col] = (f16)(acc[s][c][r] * dl[rl]);
            }
        }
    }
    __syncthreads();

    constexpr int CPR = OUT / 8;          // 16B chunks per row
    for (int j = t; j < 64 * CPR; j += 256) {
        int rl = j / CPR;
        if (row0 + rl < N)
            *(f16x8*)&M[(size_t)(row0 + rl) * OUT + (j % CPR) * 8] =
                *(const f16x8*)&ot[(size_t)j * 8];
    }
}

// ------------------------------ aggregation --------------------------------
// HALF-WAVE per node (2 nodes/wave, 8 nodes/block). Within a half: 2 quarters
// (16 lanes x f16x8 = 256B row) x unroll 8 = 16 edges per masked round,
// 8 row-loads in flight per wave. Cross-quarter combine: shfl_xor(16).
__global__ __launch_bounds__(256) void k_agg128_f16(const f16* __restrict__ M16,
                                                    const int* __restrict__ offs,
                                                    const int* __restrict__ srcs,
                                                    const float* __restrict__ dinv,
                                                    const float* __restrict__ bias,
                                                    f16* __restrict__ H16, int N) {
    const int lane = threadIdx.x & (WAVE - 1);
    const int sub  = lane >> 5;            // half 0/1
    const int hl   = lane & 31;            // lane within half
    const int q    = hl >> 4;              // quarter within half: 0/1
    const int fl   = lane & 15;            // feature lane
    const int fo   = fl * 8;               // feats fo..fo+7
    const int node = blockIdx.x * 8 + (threadIdx.x >> 6) * 2 + sub;
    if (node >= N) return;

    float a[8] = {0.f, 0.f, 0.f, 0.f, 0.f, 0.f, 0.f, 0.f};
    if (q == 0) {   // self-loop term
        f16x8 v = *(const f16x8*)&M16[(size_t)node * 128 + fo];
#pragma unroll
        for (int i = 0; i < 8; ++i) a[i] = (float)v[i];
    }

    const int e0 = offs[node], e1 = offs[node + 1];
    for (int base = e0; base < e1; base += 16) {
        int   s[8];
        float w[8];
#pragma unroll
        for (int j = 0; j < 8; ++j) {
            int i = base + 2 * j + q;
            bool ok = i < e1;
            s[j] = srcs[ok ? i : e0];
            w[j] = ok ? 1.f : 0.f;
        }
        f16x8 v[8];
#pragma unroll
        for (int j = 0; j < 8; ++j)
            v[j] = *(const f16x8*)&M16[(size_t)s[j] * 128 + fo];
#pragma unroll
        for (int j = 0; j < 8; ++j)
#pragma unroll
            for (int i = 0; i < 8; ++i)
                a[i] += w[j] * (float)v[j][i];
    }

#pragma unroll
    for (int i = 0; i < 8; ++i) a[i] += __shfl_xor(a[i], 16);

    if (q == 0) {
        const float dn = dinv[node];
        float4 b0 = *(const float4*)&bias[fo];
        float4 b1 = *(const float4*)&bias[fo + 4];
        f16x8 o;
        o[0] = (f16)fmaxf(a[0] * dn + b0.x, 0.f);
        o[1] = (f16)fmaxf(a[1] * dn + b0.y, 0.f);
        o[2] = (f16)fmaxf(a[2] * dn + b0.z, 0.f);
        o[3] = (f16)fmaxf(a[3] * dn + b0.w, 0.f);
        o[4] = (f16)fmaxf(a[4] * dn + b1.x, 0.f);
        o[5] = (f16)fmaxf(a[5] * dn + b1.y, 0.f);
        o[6] = (f16)fmaxf(a[6] * dn + b1.z, 0.f);
        o[7] = (f16)fmaxf(a[7] * dn + b1.w, 0.f);
        *(f16x8*)&H16[(size_t)node * 128 + fo] = o;
    }
}

// Final layer: 64 feats (128B row = 16 lanes x f16x4); half-wave per node,
// 16 edges per masked round; fused bias + log_softmax.
__global__ __launch_bounds__(256) void k_agg64_lsm(const f16* __restrict__ M16,
                                                   const int* __restrict__ offs,
                                                   const int* __restrict__ srcs,
                                                   const float* __restrict__ dinv,
                                                   const float* __restrict__ bias,
                                                   float* __restrict__ Y, int N) {
    const int lane = threadIdx.x & (WAVE - 1);
    const int sub  = lane >> 5;
    const int hl   = lane & 31;
    const int q    = hl >> 4;
    const int fl   = lane & 15;            // classes 4*fl .. 4*fl+3
    const int fo   = fl * 4;
    const int node = blockIdx.x * 8 + (threadIdx.x >> 6) * 2 + sub;
    if (node >= N) return;

    float a[4] = {0.f, 0.f, 0.f, 0.f};
    if (q == 0) {
        f16x4 v = *(const f16x4*)&M16[(size_t)node * 64 + fo];
#pragma unroll
        for (int i = 0; i < 4; ++i) a[i] = (float)v[i];
    }

    const int e0 = offs[node], e1 = offs[node + 1];
    for (int base = e0; base < e1; base += 16) {
        int   s[8];
        float w[8];
#pragma unroll
        for (int j = 0; j < 8; ++j) {
            int i = base + 2 * j + q;
            bool ok = i < e1;
            s[j] = srcs[ok ? i : e0];
            w[j] = ok ? 1.f : 0.f;
        }
        f16x4 v[8];
#pragma unroll
        for (int j = 0; j < 8; ++j)
            v[j] = *(const f16x4*)&M16[(size_t)s[j] * 64 + fo];
#pragma unroll
        for (int j = 0; j < 8; ++j)
#pragma unroll
            for (int i = 0; i < 4; ++i)
                a[i] += w[j] * (float)v[j][i];
    }

#pragma unroll
    for (int i = 0; i < 4; ++i) a[i] += __shfl_xor(a[i], 16);

    // logits + log_softmax across 64 classes held as 16 lanes x 4
    const float dn = dinv[node];
    float4 b = *(const float4*)&bias[fo];
    float v0 = a[0] * dn + b.x;
    float v1 = a[1] * dn + b.y;
    float v2 = a[2] * dn + b.z;
    float v3 = a[3] * dn + b.w;
    float m = fmaxf(fmaxf(v0, v1), fmaxf(v2, v3));
#pragma unroll
    for (int o = 8; o > 0; o >>= 1) m = fmaxf(m, __shfl_xor(m, o));   // width-16
    float s = expf(v0 - m) + expf(v1 - m) + expf(v2 - m) + expf(v3 - m);
#pragma unroll
    for (int o = 8; o > 0; o >>= 1) s += __shfl_xor(s, o);
    if (q == 0) {
        float ls = logf(s);
        float4 o4 = make_float4(v0 - m - ls, v1 - m - ls, v2 - m - ls, v3 - m - ls);
        *(float4*)&Y[(size_t)node * 64 + fo] = o4;
    }
}

// ---------------------------------------------------------------------------

extern "C" void kernel_launch(void* const* d_in, const int* in_sizes, int n_in,
                              void* d_out, int out_size, void* d_ws, size_t ws_size,
                              hipStream_t stream) {
    const float* x  = (const float*)d_in[0];
    const int*   ei = (const int*)d_in[1];
    const float* W1 = (const float*)d_in[2];
    const float* b1 = (const float*)d_in[3];
    const float* W2 = (const float*)d_in[4];
    const float* b2 = (const float*)d_in[5];
    const float* Wf = (const float*)d_in[6];
    const float* bf = (const float*)d_in[7];
    float* out = (float*)d_out;

    const int N = in_sizes[0] / 128;
    const int E = in_sizes[1] / 2;
    const int* src = ei;
    const int* dst = ei + E;

    char* ws = (char*)d_ws;
    auto alloc = [&](size_t bytes) -> void* {
        void* p = ws;
        ws += (bytes + 255) & ~(size_t)255;
        return p;
    };
    const int numB = (N + 1023) / 1024;
    int*   cnt    = (int*)alloc((size_t)N * 4);
    int*   cursor = (int*)alloc((size_t)N * 4);
    int*   offs   = (int*)alloc((size_t)(N + 1) * 4);
    float* dinv   = (float*)alloc((size_t)N * 4);
    int*   part   = (int*)alloc((size_t)numB * 4);
    int*   src_s  = (int*)alloc((size_t)E * 4);
    f16*   m16    = (f16*)alloc((size_t)N * 128 * 2);
    f16*   h16    = (f16*)alloc((size_t)N * 128 * 2);
    f16*   Wt1    = (f16*)alloc(128 * 128 * 2);
    f16*   Wt2    = (f16*)alloc(128 * 128 * 2);
    f16*   Wtf    = (f16*)alloc(128 * 64 * 2);

    hipMemsetAsync(cnt, 0, (size_t)N * 4, stream);

    const int TB = 256;
    k_count<<<(E + TB - 1) / TB, TB, 0, stream>>>(dst, E, cnt, N);
    k_blocksum<<<numB, 256, 0, stream>>>(cnt, N, part);
    k_blockscan<<<numB, 256, 0, stream>>>(cnt, N, part, numB, offs, dinv, cursor);
    k_scatter<<<(E + TB - 1) / TB, TB, 0, stream>>>(src, dst, E, offs, cursor, src_s, N);
    k_cvt_w_all<<<160, 256, 0, stream>>>(W1, W2, Wf, Wt1, Wt2, Wtf);

    const int gemm_grid = (N + 63) / 64;
    const int agg_grid  = (N + 7) / 8;

    k_gemm_mfma<128, true><<<gemm_grid, 256, 0, stream>>>(x, Wt1, dinv, m16, N);
    k_agg128_f16<<<agg_grid, 256, 0, stream>>>(m16, offs, src_s, dinv, b1, h16, N);

    k_gemm_mfma<128, false><<<gemm_grid, 256, 0, stream>>>(h16, Wt2, dinv, m16, N);
    k_agg128_f16<<<agg_grid, 256, 0, stream>>>(m16, offs, src_s, dinv, b2, h16, N);

    k_gemm_mfma<64, false><<<gemm_grid, 256, 0, stream>>>(h16, Wtf, dinv, m16, N);
    k_agg64_lsm<<<agg_grid, 256, 0, stream>>>(m16, offs, src_s, dinv, bf, out, N);
}

// Round 7
// 201.179 us; speedup vs baseline: 2.2957x; 1.0016x over previous
//
#include <hip/hip_runtime.h>
#include <cstdint>
#include <cstddef>

// ---------------------------------------------------------------------------
// 3-layer GCN, fp16 message pipeline:
//   m' = (h @ W) * dinv[row]      (MFMA f16 GEMM, fp32 accum, fp16 out)
//   h' = relu(dinv[n] * (m'[n] + sum_{e->n} m'[src]) + b)   (fp16 out)
// final layer: logits fp32 + log_softmax.
// CSR-by-dst built per call (zero -> count -> scan -> scatter).
// NOTE: cnt is zeroed by a custom kernel, NOT hipMemsetAsync — the rocclr
// fill kernel for small buffers runs on a tiny grid (~42us for 200KB!).
// Aggregation: half-wave per node; 16 lanes x f16x8 per edge row, 16 edges
// per masked round, 8 row-loads in flight per wave.
// GEMM layer 1 reads fp32 X directly (cvt fused into fragment load).
// ---------------------------------------------------------------------------

#define WAVE 64
typedef _Float16 f16;
typedef f16  f16x2 __attribute__((ext_vector_type(2)));
typedef f16  f16x4 __attribute__((ext_vector_type(4)));
typedef f16  f16x8 __attribute__((ext_vector_type(8)));
typedef float f32x4 __attribute__((ext_vector_type(4)));

// ------------------------------ setup --------------------------------------

__global__ void k_zero(int4* __restrict__ p, int n4) {
    int i = blockIdx.x * blockDim.x + threadIdx.x;
    if (i < n4) p[i] = make_int4(0, 0, 0, 0);
}

__global__ void k_count(const int* __restrict__ dst, int E, int* __restrict__ cnt, int N) {
    int e = blockIdx.x * blockDim.x + threadIdx.x;
    if (e >= E) return;
    int d = dst[e];
    if (d >= 0 && d < N) atomicAdd(&cnt[d], 1);
}

__global__ __launch_bounds__(256) void k_blocksum(const int* __restrict__ cnt, int N,
                                                  int* __restrict__ partial) {
    const int t  = threadIdx.x;
    const int b  = blockIdx.x;
    const int i0 = b * 1024 + t * 4;
    int s = 0;
#pragma unroll
    for (int j = 0; j < 4; ++j) {
        int i = i0 + j;
        if (i < N) s += cnt[i];
    }
#pragma unroll
    for (int o = 32; o > 0; o >>= 1) s += __shfl_xor(s, o);
    __shared__ int ws[4];
    if ((t & 63) == 0) ws[t >> 6] = s;
    __syncthreads();
    if (t == 0) partial[b] = ws[0] + ws[1] + ws[2] + ws[3];
}

// local scan + base (base = sum of partials[0..b), reduced in-kernel by wave 0);
// also emits dinv and zeroes cursor; last block writes offs[N].
__global__ __launch_bounds__(256) void k_blockscan(const int* __restrict__ cnt, int N,
                                                   const int* __restrict__ partial, int numB,
                                                   int* __restrict__ offs,
                                                   float* __restrict__ dinv,
                                                   int* __restrict__ cursor) {
    const int t  = threadIdx.x;
    const int b  = blockIdx.x;
    const int i0 = b * 1024 + t * 4;
    __shared__ int sbase;
    __shared__ int ws[4];

    if (t < 64) {           // wave 0: base = sum partial[0..b)
        int v = 0;
        for (int i = t; i < b; i += 64) v += partial[i];
#pragma unroll
        for (int o = 32; o > 0; o >>= 1) v += __shfl_xor(v, o);
        if (t == 0) sbase = v;
    }

    int c[4];
    int tsum = 0;
#pragma unroll
    for (int j = 0; j < 4; ++j) {
        int i = i0 + j;
        c[j] = (i < N) ? cnt[i] : 0;
        tsum += c[j];
    }
    int incl = tsum;
#pragma unroll
    for (int o = 1; o < 64; o <<= 1) {
        int u = __shfl_up(incl, o);
        if ((t & 63) >= o) incl += u;
    }
    const int wid = t >> 6;
    if ((t & 63) == 63) ws[wid] = incl;
    __syncthreads();
    int wbase = 0;
    for (int w = 0; w < wid; ++w) wbase += ws[w];
    int run = sbase + wbase + (incl - tsum);
#pragma unroll
    for (int j = 0; j < 4; ++j) {
        int i = i0 + j;
        if (i < N) {
            offs[i]   = run;
            run      += c[j];
            dinv[i]   = rsqrtf((float)(c[j] + 1));   // +1 self-loop
            cursor[i] = 0;
        }
    }
    if (b == numB - 1 && t == 0)
        offs[N] = sbase + ws[0] + ws[1] + ws[2] + ws[3];
}

__global__ void k_scatter(const int* __restrict__ src, const int* __restrict__ dst, int E,
                          const int* __restrict__ offsets, int* __restrict__ cursor,
                          int* __restrict__ src_s, int N) {
    int e = blockIdx.x * blockDim.x + threadIdx.x;
    if (e >= E) return;
    int d = dst[e], s = src[e];
    if (d < 0 || d >= N || s < 0 || s >= N) return;
    int p = offsets[d] + atomicAdd(&cursor[d], 1);
    src_s[p] = s;
}

// All three weight transposes in one launch.
// Wt[n][k] = (f16) W[k][n]; W1/W2: 128x128, Wf: 128x64.
__global__ void k_cvt_w_all(const float* __restrict__ W1, const float* __restrict__ W2,
                            const float* __restrict__ Wf,
                            f16* __restrict__ Wt1, f16* __restrict__ Wt2,
                            f16* __restrict__ Wtf) {
    int i = blockIdx.x * 256 + threadIdx.x;
    if (i < 16384) {
        int n = i >> 7, k = i & 127;
        Wt1[i] = (f16)W1[k * 128 + n];
    } else if (i < 32768) {
        int j = i - 16384;
        int n = j >> 7, k = j & 127;
        Wt2[j] = (f16)W2[k * 128 + n];
    } else if (i < 40960) {
        int j = i - 32768;
        int n = j >> 7, k = j & 127;
        Wtf[j] = (f16)Wf[k * 64 + n];
    }
}

// ------------------------------ MFMA GEMM ----------------------------------
// M16[m][n] = ( A[m][:] @ W[:][n] ) * dinv[m],  K=128 fixed.
// AF32: A is fp32 (layer 1, conversion fused into fragment load).
template <int OUT, bool AF32>
__global__ __launch_bounds__(256) void k_gemm_mfma(const void* __restrict__ Av,
                                                   const f16* __restrict__ Wt,
                                                   const float* __restrict__ dinv,
                                                   f16* __restrict__ M,
                                                   int N) {
    constexpr int K  = 128;
    constexpr int CW = OUT / 64;          // col-tiles per wave (2 or 1)
    __shared__ char smem[OUT * K * 2];    // W (swizzled), then reused as out-tile
    __shared__ float dl[64];

    const int t    = threadIdx.x;
    const int w    = t >> 6;
    const int lane = t & 63;
    const int ln   = lane & 15;
    const int lh   = lane >> 4;
    const int row0 = blockIdx.x * 64;

    {
        constexpr int NCH = OUT * 16;     // 16 x 16B chunks per 256B row
        for (int j = t; j < NCH; j += 256) {
            int n = j >> 4;
            uint32_t byte = (uint32_t)j * 16;
            uint32_t swz  = byte ^ (uint32_t)((n & 7) << 4);
            *(f16x8*)(smem + swz) = *(const f16x8*)&Wt[(size_t)j * 8];
        }
        if (t < 64) {
            int r = row0 + t;
            dl[t] = dinv[r < N ? r : (N - 1)];
        }
    }
    __syncthreads();

    f16x8 bfr[CW][4];
    const int c0 = w * CW;
#pragma unroll
    for (int c = 0; c < CW; ++c) {
        int n = (c0 + c) * 16 + ln;
#pragma unroll
        for (int q = 0; q < 4; ++q) {
            uint32_t byte = (uint32_t)(n * 256 + q * 64 + lh * 16);
            uint32_t swz  = byte ^ (uint32_t)((n & 7) << 4);
            bfr[c][q] = *(const f16x8*)(smem + swz);
        }
    }
    __syncthreads();

    f32x4 acc[4][CW];
#pragma unroll
    for (int s = 0; s < 4; ++s)
#pragma unroll
        for (int c = 0; c < CW; ++c)
            acc[s][c] = f32x4{0.f, 0.f, 0.f, 0.f};

#pragma unroll
    for (int s = 0; s < 4; ++s) {
        int m = row0 + s * 16 + ln;
        const size_t mrow = (size_t)(m < N ? m : (N - 1)) * K;
#pragma unroll
        for (int q = 0; q < 4; ++q) {
            f16x8 a;
            if constexpr (AF32) {
                const float* ap = (const float*)Av + mrow + q * 32 + lh * 8;
                float4 x0 = *(const float4*)ap;
                float4 x1 = *(const float4*)(ap + 4);
                a = f16x8{ (f16)x0.x, (f16)x0.y, (f16)x0.z, (f16)x0.w,
                           (f16)x1.x, (f16)x1.y, (f16)x1.z, (f16)x1.w };
            } else {
                a = *(const f16x8*)((const f16*)Av + mrow + q * 32 + lh * 8);
            }
#pragma unroll
            for (int c = 0; c < CW; ++c)
                acc[s][c] = __builtin_amdgcn_mfma_f32_16x16x32_f16(a, bfr[c][q], acc[s][c], 0, 0, 0);
        }
    }

    f16* ot = (f16*)smem;
#pragma unroll
    for (int s = 0; s < 4; ++s) {
#pragma unroll
        for (int c = 0; c < CW; ++c) {
            int col = (c0 + c) * 16 + ln;
#pragma unroll
            for (int r = 0; r < 4; ++r) {
                int rl = s * 16 + lh * 4 + r;
                ot[rl * OUT + col] = (f16)(acc[s][c][r] * dl[rl]);
            }
        }
    }
    __syncthreads();

    constexpr int CPR = OUT / 8;          // 16B chunks per row
    for (int j = t; j < 64 * CPR; j += 256) {
        int rl = j / CPR;
        if (row0 + rl < N)
            *(f16x8*)&M[(size_t)(row0 + rl) * OUT + (j % CPR) * 8] =
                *(const f16x8*)&ot[(size_t)j * 8];
    }
}

// ------------------------------ aggregation --------------------------------
// HALF-WAVE per node (2 nodes/wave, 8 nodes/block). Within a half: 2 quarters
// (16 lanes x f16x8 = 256B row) x unroll 8 = 16 edges per masked round,
// 8 row-loads in flight per wave. Cross-quarter combine: shfl_xor(16).
__global__ __launch_bounds__(256) void k_agg128_f16(const f16* __restrict__ M16,
                                                    const int* __restrict__ offs,
                                                    const int* __restrict__ srcs,
                                                    const float* __restrict__ dinv,
                                                    const float* __restrict__ bias,
                                                    f16* __restrict__ H16, int N) {
    const int lane = threadIdx.x & (WAVE - 1);
    const int sub  = lane >> 5;            // half 0/1
    const int hl   = lane & 31;            // lane within half
    const int q    = hl >> 4;              // quarter within half: 0/1
    const int fl   = lane & 15;            // feature lane
    const int fo   = fl * 8;               // feats fo..fo+7
    const int node = blockIdx.x * 8 + (threadIdx.x >> 6) * 2 + sub;
    if (node >= N) return;

    float a[8] = {0.f, 0.f, 0.f, 0.f, 0.f, 0.f, 0.f, 0.f};
    if (q == 0) {   // self-loop term
        f16x8 v = *(const f16x8*)&M16[(size_t)node * 128 + fo];
#pragma unroll
        for (int i = 0; i < 8; ++i) a[i] = (float)v[i];
    }

    const int e0 = offs[node], e1 = offs[node + 1];
    for (int base = e0; base < e1; base += 16) {
        int   s[8];
        float w[8];
#pragma unroll
        for (int j = 0; j < 8; ++j) {
            int i = base + 2 * j + q;
            bool ok = i < e1;
            s[j] = srcs[ok ? i : e0];
            w[j] = ok ? 1.f : 0.f;
        }
        f16x8 v[8];
#pragma unroll
        for (int j = 0; j < 8; ++j)
            v[j] = *(const f16x8*)&M16[(size_t)s[j] * 128 + fo];
#pragma unroll
        for (int j = 0; j < 8; ++j)
#pragma unroll
            for (int i = 0; i < 8; ++i)
                a[i] += w[j] * (float)v[j][i];
    }

#pragma unroll
    for (int i = 0; i < 8; ++i) a[i] += __shfl_xor(a[i], 16);

    if (q == 0) {
        const float dn = dinv[node];
        float4 b0 = *(const float4*)&bias[fo];
        float4 b1 = *(const float4*)&bias[fo + 4];
        f16x8 o;
        o[0] = (f16)fmaxf(a[0] * dn + b0.x, 0.f);
        o[1] = (f16)fmaxf(a[1] * dn + b0.y, 0.f);
        o[2] = (f16)fmaxf(a[2] * dn + b0.z, 0.f);
        o[3] = (f16)fmaxf(a[3] * dn + b0.w, 0.f);
        o[4] = (f16)fmaxf(a[4] * dn + b1.x, 0.f);
        o[5] = (f16)fmaxf(a[5] * dn + b1.y, 0.f);
        o[6] = (f16)fmaxf(a[6] * dn + b1.z, 0.f);
        o[7] = (f16)fmaxf(a[7] * dn + b1.w, 0.f);
        *(f16x8*)&H16[(size_t)node * 128 + fo] = o;
    }
}

// Final layer: 64 feats (128B row = 16 lanes x f16x4); half-wave per node,
// 16 edges per masked round; fused bias + log_softmax.
__global__ __launch_bounds__(256) void k_agg64_lsm(const f16* __restrict__ M16,
                                                   const int* __restrict__ offs,
                                                   const int* __restrict__ srcs,
                                                   const float* __restrict__ dinv,
                                                   const float* __restrict__ bias,
                                                   float* __restrict__ Y, int N) {
    const int lane = threadIdx.x & (WAVE - 1);
    const int sub  = lane >> 5;
    const int hl   = lane & 31;
    const int q    = hl >> 4;
    const int fl   = lane & 15;            // classes 4*fl .. 4*fl+3
    const int fo   = fl * 4;
    const int node = blockIdx.x * 8 + (threadIdx.x >> 6) * 2 + sub;
    if (node >= N) return;

    float a[4] = {0.f, 0.f, 0.f, 0.f};
    if (q == 0) {
        f16x4 v = *(const f16x4*)&M16[(size_t)node * 64 + fo];
#pragma unroll
        for (int i = 0; i < 4; ++i) a[i] = (float)v[i];
    }

    const int e0 = offs[node], e1 = offs[node + 1];
    for (int base = e0; base < e1; base += 16) {
        int   s[8];
        float w[8];
#pragma unroll
        for (int j = 0; j < 8; ++j) {
            int i = base + 2 * j + q;
            bool ok = i < e1;
            s[j] = srcs[ok ? i : e0];
            w[j] = ok ? 1.f : 0.f;
        }
        f16x4 v[8];
#pragma unroll
        for (int j = 0; j < 8; ++j)
            v[j] = *(const f16x4*)&M16[(size_t)s[j] * 64 + fo];
#pragma unroll
        for (int j = 0; j < 8; ++j)
#pragma unroll
            for (int i = 0; i < 4; ++i)
                a[i] += w[j] * (float)v[j][i];
    }

#pragma unroll
    for (int i = 0; i < 4; ++i) a[i] += __shfl_xor(a[i], 16);

    // logits + log_softmax across 64 classes held as 16 lanes x 4
    const float dn = dinv[node];
    float4 b = *(const float4*)&bias[fo];
    float v0 = a[0] * dn + b.x;
    float v1 = a[1] * dn + b.y;
    float v2 = a[2] * dn + b.z;
    float v3 = a[3] * dn + b.w;
    float m = fmaxf(fmaxf(v0, v1), fmaxf(v2, v3));
#pragma unroll
    for (int o = 8; o > 0; o >>= 1) m = fmaxf(m, __shfl_xor(m, o));   // width-16
    float s = expf(v0 - m) + expf(v1 - m) + expf(v2 - m) + expf(v3 - m);
#pragma unroll
    for (int o = 8; o > 0; o >>= 1) s += __shfl_xor(s, o);
    if (q == 0) {
        float ls = logf(s);
        float4 o4 = make_float4(v0 - m - ls, v1 - m - ls, v2 - m - ls, v3 - m - ls);
        *(float4*)&Y[(size_t)node * 64 + fo] = o4;
    }
}

// ---------------------------------------------------------------------------

extern "C" void kernel_launch(void* const* d_in, const int* in_sizes, int n_in,
                              void* d_out, int out_size, void* d_ws, size_t ws_size,
                              hipStream_t stream) {
    const float* x  = (const float*)d_in[0];
    const int*   ei = (const int*)d_in[1];
    const float* W1 = (const float*)d_in[2];
    const float* b1 = (const float*)d_in[3];
    const float* W2 = (const float*)d_in[4];
    const float* b2 = (const float*)d_in[5];
    const float* Wf = (const float*)d_in[6];
    const float* bf = (const float*)d_in[7];
    float* out = (float*)d_out;

    const int N = in_sizes[0] / 128;
    const int E = in_sizes[1] / 2;
    const int* src = ei;
    const int* dst = ei + E;

    char* ws = (char*)d_ws;
    auto alloc = [&](size_t bytes) -> void* {
        void* p = ws;
        ws += (bytes + 255) & ~(size_t)255;
        return p;
    };
    const int numB = (N + 1023) / 1024;
    int*   cnt    = (int*)alloc((size_t)N * 4);
    int*   cursor = (int*)alloc((size_t)N * 4);
    int*   offs   = (int*)alloc((size_t)(N + 1) * 4);
    float* dinv   = (float*)alloc((size_t)N * 4);
    int*   part   = (int*)alloc((size_t)numB * 4);
    int*   src_s  = (int*)alloc((size_t)E * 4);
    f16*   m16    = (f16*)alloc((size_t)N * 128 * 2);
    f16*   h16    = (f16*)alloc((size_t)N * 128 * 2);
    f16*   Wt1    = (f16*)alloc(128 * 128 * 2);
    f16*   Wt2    = (f16*)alloc(128 * 128 * 2);
    f16*   Wtf    = (f16*)alloc(128 * 64 * 2);

    const int TB = 256;
    const int n4 = (N + 3) / 4;                 // int4 chunks covering cnt[N]
    k_zero<<<(n4 + TB - 1) / TB, TB, 0, stream>>>((int4*)cnt, n4);
    k_count<<<(E + TB - 1) / TB, TB, 0, stream>>>(dst, E, cnt, N);
    k_blocksum<<<numB, 256, 0, stream>>>(cnt, N, part);
    k_blockscan<<<numB, 256, 0, stream>>>(cnt, N, part, numB, offs, dinv, cursor);
    k_scatter<<<(E + TB - 1) / TB, TB, 0, stream>>>(src, dst, E, offs, cursor, src_s, N);
    k_cvt_w_all<<<160, 256, 0, stream>>>(W1, W2, Wf, Wt1, Wt2, Wtf);

    const int gemm_grid = (N + 63) / 64;
    const int agg_grid  = (N + 7) / 8;

    k_gemm_mfma<128, true><<<gemm_grid, 256, 0, stream>>>(x, Wt1, dinv, m16, N);
    k_agg128_f16<<<agg_grid, 256, 0, stream>>>(m16, offs, src_s, dinv, b1, h16, N);

    k_gemm_mfma<128, false><<<gemm_grid, 256, 0, stream>>>(h16, Wt2, dinv, m16, N);
    k_agg128_f16<<<agg_grid, 256, 0, stream>>>(m16, offs, src_s, dinv, b2, h16, N);

    k_gemm_mfma<64, false><<<gemm_grid, 256, 0, stream>>>(h16, Wtf, dinv, m16, N);
    k_agg64_lsm<<<agg_grid, 256, 0, stream>>>(m16, offs, src_s, dinv, bf, out, N);
}